// Round 23
// baseline (266.876 us; speedup 1.0000x reference)
//
#include <hip/hip_runtime.h>
#include <math.h>

#define NTOK 2025
#define NBS  4050   // NTOK * BS
#define BSZ  2

typedef __attribute__((ext_vector_type(8))) short bf16x8;
typedef __attribute__((ext_vector_type(4))) float f32x4;

__device__ __forceinline__ float silu_f(float v){ return v / (1.f + __expf(-v)); }

__device__ __forceinline__ unsigned short bf16_rne(float f){
  union { float f; unsigned u; } v; v.f = f;
  unsigned u = v.u;
  return (unsigned short)((u + 0x7FFFu + ((u >> 16) & 1u)) >> 16);
}
__device__ __forceinline__ float bf2f(unsigned short u){
  union { unsigned u; float f; } v; v.u = ((unsigned)u)<<16; return v.f;
}
__device__ __forceinline__ bf16x8 zero_bf8(){
  bf16x8 r;
  #pragma unroll
  for (int j=0;j<8;j++) r[j]=0;
  return r;
}
__device__ __forceinline__ float fexp2(float x){
  float r; asm("v_exp_f32 %0, %1" : "=v"(r) : "v"(x)); return r;
}
__device__ __forceinline__ unsigned cvt_pk_bf16(float lo, float hi){
  unsigned r; asm("v_cvt_pk_bf16_f32 %0, %1, %2" : "=v"(r) : "v"(lo), "v"(hi)); return r;
}

#define QSC 0.5050097642f      /* 32^(-1/4) * sqrt(log2 e) */
#define LOG2E 1.4426950408889634f

#define VPACK2(dst, stride, e0, aw, cw) \
  (dst)[(e0)*(stride)]     = ((aw) & 0xffffu) | ((cw) << 16); \
  (dst)[((e0)+1)*(stride)] = ((aw) >> 16)     | ((cw) & 0xffff0000u);

// ---------------- prologue convert ----------------
__global__ __launch_bounds__(256) void convert_kernel(
    const float* __restrict__ Wqv, const float* __restrict__ Wu, const float* __restrict__ Widv,
    const float* __restrict__ ltWo, const float* __restrict__ stWo, const float* __restrict__ saWqk,
    const float* __restrict__ saWv, const float* __restrict__ saWu, const float* __restrict__ saWo,
    const float* __restrict__ Wrel, const float* __restrict__ idemb,
    unsigned* __restrict__ outPk, unsigned short* __restrict__ outWrel, unsigned short* __restrict__ outId)
{
  int idx = blockIdx.x*256 + threadIdx.x;
  if (idx < 1605632){
    float lo, hi;
    if (idx < 163840){
      int k2 = idx/1280, n = idx - k2*1280;
      const float* W; int ldw, nn;
      if (n < 768){ W=Wqv; ldw=768; nn=n; } else { W=Wu; ldw=512; nn=n-768; }
      lo = W[(size_t)(2*k2)*ldw + nn]; hi = W[(size_t)(2*k2+1)*ldw + nn];
    } else if (idx < 229376){
      int rel = idx-163840; int k2 = rel>>9, n = rel&511;
      lo = Widv[(size_t)(2*k2)*512 + n]; hi = Widv[(size_t)(2*k2+1)*512 + n];
    } else if (idx < 753664){
      int rel = idx-229376; int k2 = rel>>9, n = rel&511;
      int kk = 2*k2;
      if (kk < 1024){ lo = ltWo[(size_t)kk*512 + n]; hi = ltWo[(size_t)(kk+1)*512 + n]; }
      else          { lo = stWo[(size_t)(kk-1024)*512 + n]; hi = stWo[(size_t)(kk-1023)*512 + n]; }
    } else if (idx < 1343488){
      int rel = idx-753664; int k2 = rel/2304, n = rel - k2*2304;
      const float* W; int ldw, nn;
      if (n < 256){ W=saWqk; ldw=256; nn=n; }
      else if (n < 1280){ W=saWv; ldw=1024; nn=n-256; }
      else { W=saWu; ldw=1024; nn=n-1280; }
      lo = W[(size_t)(2*k2)*ldw + nn]; hi = W[(size_t)(2*k2+1)*ldw + nn];
    } else {
      int rel = idx-1343488; int k2 = rel>>9, n = rel&511;
      lo = saWo[(size_t)(2*k2)*512 + n]; hi = saWo[(size_t)(2*k2+1)*512 + n];
    }
    outPk[idx] = (unsigned)bf16_rne(lo) | ((unsigned)bf16_rne(hi)<<16);
  } else if (idx < 1663232){
    int r = idx - 1605632;
    outWrel[r] = bf16_rne(Wrel[r] * QSC);
  } else if (idx < 2700032){
    int r = idx - 1663232;
    outId[r] = bf16_rne(idemb[r]);
  }
}

// ---------------- LayerNorm over C=256, bf16 out ----------------
__global__ __launch_bounds__(256) void ln256_kernel(
    const float* __restrict__ in, const float* __restrict__ g,
    const float* __restrict__ bta, unsigned short* __restrict__ out)
{
  int row = blockIdx.x;
  int t = threadIdx.x;
  float x = in[(size_t)row*256 + t];
  float s = x, s2 = x*x;
  #pragma unroll
  for (int o=32; o>0; o>>=1){ s += __shfl_xor(s,o); s2 += __shfl_xor(s2,o); }
  __shared__ float w1[4], w2[4];
  __shared__ float mean_s, rstd_s;
  int wid = t>>6, lane = t&63;
  if (lane==0){ w1[wid]=s; w2[wid]=s2; }
  __syncthreads();
  if (t==0){
    float S  = w1[0]+w1[1]+w1[2]+w1[3];
    float S2 = w2[0]+w2[1]+w2[2]+w2[3];
    float m = S*(1.f/256.f);
    float v = S2*(1.f/256.f) - m*m;
    mean_s = m; rstd_s = rsqrtf(v + 1e-5f);
  }
  __syncthreads();
  out[(size_t)row*256 + t] = bf16_rne((x-mean_s)*rstd_s*g[t] + bta[t]);
}

// ---------------- dual LayerNorm ----------------
__global__ __launch_bounds__(256) void ln_dual_kernel(
    const float* __restrict__ newt, const float* __restrict__ tgtid,
    const float* __restrict__ g1, const float* __restrict__ b1,
    const float* __restrict__ g2, const float* __restrict__ b2,
    unsigned short* __restrict__ xbuf)
{
  int row = blockIdx.x;
  int t = threadIdx.x;
  float x1 = newt[(size_t)row*256 + t];
  float x2 = tgtid[(size_t)row*256 + t];
  float s1=x1, q1=x1*x1, s2v=x2, q2=x2*x2;
  #pragma unroll
  for (int o=32; o>0; o>>=1){
    s1 += __shfl_xor(s1,o); q1 += __shfl_xor(q1,o);
    s2v += __shfl_xor(s2v,o); q2 += __shfl_xor(q2,o);
  }
  __shared__ float w[4][4];
  __shared__ float st[4];
  int wid = t>>6, lane = t&63;
  if (lane==0){ w[wid][0]=s1; w[wid][1]=q1; w[wid][2]=s2v; w[wid][3]=q2; }
  __syncthreads();
  if (t==0){
    float S1=0,Q1=0,S2=0,Q2=0;
    #pragma unroll
    for (int i=0;i<4;i++){ S1+=w[i][0]; Q1+=w[i][1]; S2+=w[i][2]; Q2+=w[i][3]; }
    float m1=S1*(1.f/256.f), v1=Q1*(1.f/256.f)-m1*m1;
    float m2=S2*(1.f/256.f), v2=Q2*(1.f/256.f)-m2*m2;
    st[0]=m1; st[1]=rsqrtf(v1+1e-5f); st[2]=m2; st[3]=rsqrtf(v2+1e-5f);
  }
  __syncthreads();
  xbuf[(size_t)row*512 + t]       = bf16_rne((x1-st[0])*st[1]*g1[t] + b1[t]);
  xbuf[(size_t)row*512 + 256 + t] = bf16_rne((x2-st[2])*st[3]*g2[t] + b2[t]);
}

// ---------------- MFMA bf16 GEMM, BK=64, fused routing epilogues ----------------
template<int ROUTE>
__global__ __launch_bounds__(256) void gemm_mfma_kernel(
    const unsigned short* __restrict__ A, int lda,
    const unsigned* __restrict__ Bpk, int ldn,
    const float* __restrict__ bias0, const float* __restrict__ bias1, const float* __restrict__ bias2,
    void* __restrict__ P0, void* __restrict__ P1, void* __restrict__ P2,
    int M, int K)
{
  __shared__ __align__(16) unsigned short As[2*64*40];
  __shared__ __align__(16) unsigned Bst[2*64*20];
  const int t = threadIdx.x;
  const int w = t>>6, l = t&63, lr = l&15, lg = l>>4;
  const int m0 = blockIdx.x*64, n0 = blockIdx.y*64;

  const int ar = t>>2,  ak  = (t&3)<<3;
  const int bc = t&63,  bk4 = (t>>6)<<2;

  f32x4 acc[4];
  #pragma unroll
  for (int i=0;i<4;i++) acc[i]=(f32x4){0.f,0.f,0.f,0.f};

  bf16x8 aR0 = zero_bf8(), aR1 = zero_bf8();
  unsigned bR[8];
  {
    if (m0+ar < M){
      aR0 = *reinterpret_cast<const bf16x8*>(&A[(size_t)(m0+ar)*lda + ak]);
      aR1 = *reinterpret_cast<const bf16x8*>(&A[(size_t)(m0+ar)*lda + 32 + ak]);
    }
    #pragma unroll
    for (int j=0;j<4;j++){
      bR[j]   = Bpk[(size_t)(bk4+j)*ldn + n0 + bc];
      bR[4+j] = Bpk[(size_t)(16+bk4+j)*ldn + n0 + bc];
    }
  }

  const int NR = K>>6;
  for (int rr=0; rr<NR; rr++){
    __syncthreads();
    {
      *reinterpret_cast<bf16x8*>(&As[0*2560 + ar*40 + ak]) = aR0;
      *reinterpret_cast<bf16x8*>(&As[1*2560 + ar*40 + ak]) = aR1;
      *reinterpret_cast<uint4*>(&Bst[0*1280 + bc*20 + bk4]) = make_uint4(bR[0],bR[1],bR[2],bR[3]);
      *reinterpret_cast<uint4*>(&Bst[1*1280 + bc*20 + bk4]) = make_uint4(bR[4],bR[5],bR[6],bR[7]);
    }
    __syncthreads();
    if (rr+1 < NR){
      int k0 = (rr+1)<<6;
      if (m0+ar < M){
        aR0 = *reinterpret_cast<const bf16x8*>(&A[(size_t)(m0+ar)*lda + k0 + ak]);
        aR1 = *reinterpret_cast<const bf16x8*>(&A[(size_t)(m0+ar)*lda + k0 + 32 + ak]);
      }
      #pragma unroll
      for (int j=0;j<4;j++){
        bR[j]   = Bpk[(size_t)((k0>>1)+bk4+j)*ldn + n0 + bc];
        bR[4+j] = Bpk[(size_t)((k0>>1)+16+bk4+j)*ldn + n0 + bc];
      }
    }
    bf16x8 af0 = *reinterpret_cast<const bf16x8*>(&As[0*2560 + (w*16+lr)*40 + lg*8]);
    #pragma unroll
    for (int cf=0; cf<4; cf++){
      bf16x8 bf = *reinterpret_cast<const bf16x8*>(&Bst[0*1280 + (cf*16+lr)*20 + lg*4]);
      acc[cf] = __builtin_amdgcn_mfma_f32_16x16x32_bf16(af0, bf, acc[cf], 0,0,0);
    }
    bf16x8 af1 = *reinterpret_cast<const bf16x8*>(&As[1*2560 + (w*16+lr)*40 + lg*8]);
    #pragma unroll
    for (int cf=0; cf<4; cf++){
      bf16x8 bf = *reinterpret_cast<const bf16x8*>(&Bst[1*1280 + (cf*16+lr)*20 + lg*4]);
      acc[cf] = __builtin_amdgcn_mfma_f32_16x16x32_bf16(af1, bf, acc[cf], 0,0,0);
    }
  }

  #pragma unroll
  for (int cf=0; cf<4; cf++){
    int col = n0 + cf*16 + lr;
    float bb;
    if (ROUTE==0) bb = bias0[col];
    if (ROUTE==1) bb = (col<768) ? bias0[col] : bias1[col-768];
    if (ROUTE==2) bb = (col<256) ? bias0[col] : (col<1280 ? bias1[col-256] : bias2[col-1280]);
    if (ROUTE==3) bb = bias0[col] + bias1[col];
    if (ROUTE==4) bb = bias0[col];
    #pragma unroll
    for (int r=0;r<4;r++){
      int row = m0 + w*16 + lg*4 + r;
      if (row >= M) continue;
      float v = acc[cf][r] + bb;
      if (ROUTE==0){
        ((unsigned short*)P0)[(size_t)row*1024 + 512 + col] = bf16_rne(silu_f(v));
      }
      if (ROUTE==1){
        if (col < 256)      ((unsigned short*)P0)[(size_t)row*256 + col] = bf16_rne(v*QSC);
        else if (col < 768) ((unsigned short*)P1)[(size_t)row*1024 + col-256] = bf16_rne(silu_f(v));
        else                ((unsigned short*)P2)[(size_t)row*512 + col-768] = bf16_rne(silu_f(v));
      }
      if (ROUTE==2){
        if (col < 256)       ((unsigned short*)P0)[(size_t)row*256 + col] = bf16_rne(v*QSC);
        else if (col < 1280) ((unsigned short*)P1)[(size_t)row*1024 + col-256] = bf16_rne(silu_f(v));
        else                 ((unsigned short*)P2)[(size_t)row*1024 + col-1280] = bf16_rne(silu_f(v));
      }
      if (ROUTE==3){
        if (col < 256) ((float*)P0)[(size_t)row*256 + col] = v + ((const float*)P2)[(size_t)row*256 + col];
        else           ((float*)P1)[(size_t)row*256 + col-256] = v;
      }
      if (ROUTE==4){
        if (col < 256) ((float*)P0)[(size_t)row*256 + col] = v + ((const float*)P1)[(size_t)row*256 + col];
        else           ((float*)P0)[(size_t)NBS*256 + (size_t)row*256 + col-256] = v + ((const float*)P2)[(size_t)row*256 + col-256];
      }
    }
  }
}

// ---------------- fused attention: compact-LDS flash (3 blocks/CU) + local (8-wave)
// Round-20 flash path + T5 s_setprio around MFMA clusters.
__global__ __launch_bounds__(512) void attn_fused_kernel(
    const unsigned short* __restrict__ Qp, const unsigned short* __restrict__ Vp,
    const unsigned short* __restrict__ Ug, unsigned short* __restrict__ OutF,
    int gateW, int ldo,
    const unsigned short* __restrict__ WrelBf, const float* __restrict__ brel_g,
    unsigned short* __restrict__ OutL)
{
  __shared__ __align__(16) unsigned char smem[53248];
  const int t = threadIdx.x;
  const f32x4 zero4 = (f32x4){0.f,0.f,0.f,0.f};
  const uint4 z4 = make_uint4(0,0,0,0);

  int fbid = 0, lbid = 0;
  bool isFlash;
  if (gridDim.x == 512){
    isFlash = true; fbid = blockIdx.x;
  } else {
    int bidx = blockIdx.x;
    if (bidx < 256){ isFlash = true;  fbid = bidx; }
    else if (bidx < 616){ isFlash = false; lbid = bidx - 256; }
    else if (bidx < 872){ isFlash = true;  fbid = bidx - 360; }
    else { isFlash = false; lbid = bidx - 512; }
  }

  if (isFlash){
    // ================= FLASH PATH =================
    unsigned short* Ks  = (unsigned short*)smem;           // 2*64*40 u16 = 10240B
    unsigned*       Vt2 = (unsigned*)(smem + 10240);       // 2*128*32 u32 = 32768B
    unsigned short* Pb  = (unsigned short*)(smem + 43008); // 8*16*40 u16 = 10240B

    const int w  = t >> 6;
    const int half = w >> 2;
    const int wl = w & 3;
    const int th = t & 255;
    const int l  = t & 63;
    const int lr = l & 15;
    const int lg = l >> 4;

    const int bid = fbid;
    const int xcd = bid & 7, rrr = bid >> 3;
    const int grp = (rrr >> 5)*8 + xcd;
    const int h = grp >> 1, b = grp & 1;
    const int r0 = (rrr & 31) * 64;

    unsigned short* KsH = &Ks[half*64*40];
    unsigned*       VtH = &Vt2[half*128*32];

    bf16x8 qf = zero_bf8();
    {
      int n = r0 + wl*16 + lr;
      if (n < NTOK) qf = *reinterpret_cast<const bf16x8*>(&Qp[(size_t)(n*2+b)*256 + h*32 + lg*8]);
    }

    f32x4 acc[8];
    #pragma unroll
    for (int i=0;i<8;i++) acc[i] = (f32x4){0.f,0.f,0.f,0.f};
    float lrun = 0.f;

    const int key = th & 63, kdh = th >> 6;
    const int kp  = th & 31, vdh = th >> 5;
    const int ktBase = half*16;

    bf16x8 kReg = zero_bf8();
    uint4 vA0=z4, vA1=z4, vC0=z4, vC1=z4;
    {
      int k0p = ktBase*64;
      int n = k0p + key;
      if (n < NTOK) kReg = *reinterpret_cast<const bf16x8*>(&Qp[(size_t)(n*2+b)*256 + h*32 + kdh*8]);
      int n0i = k0p + kp*2, n1i = n0i + 1;
      const uint4* v0 = reinterpret_cast<const uint4*>(Vp + (size_t)(n0i*2+b)*1024 + h*128 + vdh*16);
      const uint4* v1 = reinterpret_cast<const uint4*>(Vp + (size_t)(n1i*2+b)*1024 + h*128 + vdh*16);
      if (n0i < NTOK){ vA0 = v0[0]; vA1 = v0[1]; }
      if (n1i < NTOK){ vC0 = v1[0]; vC1 = v1[1]; }
    }

    for (int it=0; it<16; it++){
      const int k0 = (ktBase + it)*64;
      __syncthreads();

      *reinterpret_cast<bf16x8*>(&KsH[key*40 + kdh*8]) = kReg;
      { // V tile pack, stride-32 XOR swizzled
        unsigned* Vb = VtH + (vdh*16)*32;
        #define VP2S(e0, aw, cw) \
          Vb[(e0)*32   + (kp ^ (((e0)&7)<<2))]       = ((aw)&0xffffu) | ((cw)<<16); \
          Vb[((e0)+1)*32 + (kp ^ ((((e0)+1)&7)<<2))] = ((aw)>>16)     | ((cw)&0xffff0000u);
        VP2S(0,  vA0.x, vC0.x)
        VP2S(2,  vA0.y, vC0.y)
        VP2S(4,  vA0.z, vC0.z)
        VP2S(6,  vA0.w, vC0.w)
        VP2S(8,  vA1.x, vC1.x)
        VP2S(10, vA1.y, vC1.y)
        VP2S(12, vA1.z, vC1.z)
        VP2S(14, vA1.w, vC1.w)
        #undef VP2S
      }
      __syncthreads();

      if (it+1 < 16){
        int k0n = k0 + 64;
        int n = k0n + key;
        kReg = zero_bf8();
        if (n < NTOK) kReg = *reinterpret_cast<const bf16x8*>(&Qp[(size_t)(n*2+b)*256 + h*32 + kdh*8]);
        int n0i = k0n + kp*2, n1i = n0i + 1;
        const uint4* v0 = reinterpret_cast<const uint4*>(Vp + (size_t)(n0i*2+b)*1024 + h*128 + vdh*16);
        const uint4* v1 = reinterpret_cast<const uint4*>(Vp + (size_t)(n1i*2+b)*1024 + h*128 + vdh*16);
        vA0=z4; vA1=z4; vC0=z4; vC1=z4;
        if (n0i < NTOK){ vA0 = v0[0]; vA1 = v0[1]; }
        if (n1i < NTOK){ vC0 = v1[0]; vC1 = v1[1]; }
      }

      // swapped QK^T
      f32x4 s[4];
      __builtin_amdgcn_s_setprio(1);
      #pragma unroll
      for (int f=0;f<4;f++){
        bf16x8 kb = *reinterpret_cast<const bf16x8*>(&KsH[(16*f + lr)*40 + lg*8]);
        s[f] = __builtin_amdgcn_mfma_f32_16x16x32_bf16(kb, qf, zero4, 0, 0, 0);
      }
      __builtin_amdgcn_s_setprio(0);
      #pragma unroll
      for (int f=0;f<4;f++)
        #pragma unroll
        for (int r=0;r<4;r++)
          s[f][r] = fexp2(s[f][r]);
      if (k0 + 64 > NTOK){
        #pragma unroll
        for (int f=0;f<4;f++)
          #pragma unroll
          for (int r=0;r<4;r++)
            if (k0 + 16*f + 4*lg + r >= NTOK) s[f][r] = 0.f;
      }

      { // lane-local row sum + 2 shfl
        float ps = 0.f;
        #pragma unroll
        for (int f=0;f<4;f++){
          ps += s[f][0]; ps += s[f][1]; ps += s[f][2]; ps += s[f][3];
        }
        ps += __shfl_xor(ps, 16);
        ps += __shfl_xor(ps, 32);
        lrun += ps;
      }

      unsigned short* pb = &Pb[w*16*40];
      // sub-phase A: keys 0..31
      #pragma unroll
      for (int f=0;f<2;f++){
        unsigned w0 = cvt_pk_bf16(s[f][0], s[f][1]);
        unsigned w1 = cvt_pk_bf16(s[f][2], s[f][3]);
        *reinterpret_cast<uint2*>(&pb[lr*40 + 16*f + 4*lg]) = make_uint2(w0, w1);
      }
      {
        bf16x8 pa0 = *reinterpret_cast<const bf16x8*>(&pb[lr*40 + lg*8]);
        __builtin_amdgcn_s_setprio(1);
        #pragma unroll
        for (int c=0;c<8;c++){
          bf16x8 vb0 = *reinterpret_cast<const bf16x8*>(&VtH[(c*16+lr)*32 + ((lg*4) ^ ((lr&7)<<2))]);
          acc[c] = __builtin_amdgcn_mfma_f32_16x16x32_bf16(pa0, vb0, acc[c], 0, 0, 0);
        }
        __builtin_amdgcn_s_setprio(0);
      }
      // sub-phase B: keys 32..63
      #pragma unroll
      for (int f=2;f<4;f++){
        unsigned w0 = cvt_pk_bf16(s[f][0], s[f][1]);
        unsigned w1 = cvt_pk_bf16(s[f][2], s[f][3]);
        *reinterpret_cast<uint2*>(&pb[lr*40 + 16*(f-2) + 4*lg]) = make_uint2(w0, w1);
      }
      {
        bf16x8 pa1 = *reinterpret_cast<const bf16x8*>(&pb[lr*40 + lg*8]);
        __builtin_amdgcn_s_setprio(1);
        #pragma unroll
        for (int c=0;c<8;c++){
          bf16x8 vb1 = *reinterpret_cast<const bf16x8*>(&VtH[(c*16+lr)*32 + ((16 + lg*4) ^ ((lr&7)<<2))]);
          acc[c] = __builtin_amdgcn_mfma_f32_16x16x32_bf16(pa1, vb1, acc[c], 0, 0, 0);
        }
        __builtin_amdgcn_s_setprio(0);
      }
    }

    // ---- combine halves: plain sums (swizzled exchange) ----
    __syncthreads();
    float* exA = (float*)Vt2;
    float* exM = (float*)Ks;
    const int slot = wl*64 + l;
    if (half == 1){
      exM[slot] = lrun;
      #pragma unroll
      for (int c=0;c<8;c++)
        #pragma unroll
        for (int r=0;r<4;r++)
          exA[slot*32 + ((c*4+r) ^ (slot&31))] = acc[c][r];
    }
    __syncthreads();
    if (half == 1) return;

    lrun += exM[slot];
    #pragma unroll
    for (int c=0;c<8;c++)
      #pragma unroll
      for (int r=0;r<4;r++)
        acc[c][r] += exA[slot*32 + ((c*4+r) ^ (slot&31))];

    float linv[4];
    #pragma unroll
    for (int r=0;r<4;r++) linv[r] = 1.f / __shfl(lrun, lg*4 + r);

    #pragma unroll
    for (int r=0;r<4;r++){
      int n = r0 + wl*16 + lg*4 + r;
      if (n >= NTOK) continue;
      size_t rb = (size_t)(n*2+b);
      const unsigned short* ugr = Ug + rb*gateW;
      unsigned short* orow = OutF + rb*ldo + h*128;
      #pragma unroll
      for (int c=0;c<8;c++){
        int dv = c*16 + lr;
        int ch = h*128 + dv;
        float v = acc[c][r]*linv[r];
        if (ch < gateW) v *= bf2f(ugr[ch]);
        orow[dv] = bf16_rne(v);
      }
    }
    return;
  }

  // ================= LOCAL PATH (8 waves) =================
  {
    unsigned short* scb = (unsigned short*)smem;           // 45*226 u16
    float* ubuf = (float*)(smem + 20352);
    unsigned short* Qs = (unsigned short*)ubuf;            // [48*40]
    unsigned short* Wk = Qs + 48*40;
    unsigned short* Abuf = (unsigned short*)ubuf;          // phase C P~ [48][72 u16]
    unsigned*       Vt2L = (unsigned*)(ubuf + 1728);       // phase C V^ [128][36]

    const int w = t>>6, l = t&63;
    const int lr = l&15, lg = l>>4;

    const int xcd = lbid & 7, rrr = lbid >> 3;
    const int grp = (rrr/45)*8 + xcd;
    const int h = grp >> 1, b = grp & 1;
    const int y = rrr % 45;

    const unsigned short NEGBF = bf16_rne(-1e9f);

    for (int i=t; i<45*226; i+=512) scb[i] = NEGBF;

    for (int idx=t; idx<192; idx+=512){
      int row = idx>>2, c = (idx&3)<<3;
      bf16x8 v = zero_bf8();
      if (row < 45) v = *reinterpret_cast<const bf16x8*>(&Qp[(size_t)((y*45+row)*2+b)*256 + h*32 + c]);
      *reinterpret_cast<bf16x8*>(&Qs[row*40 + c]) = v;
    }
    for (int idx=t; idx<960; idx+=512){
      int row = idx>>2, c = (idx&3)<<3;
      bf16x8 v = zero_bf8();
      if (row < 225) v = *reinterpret_cast<const bf16x8*>(&WrelBf[((size_t)h*225 + row)*32 + c]);
      *reinterpret_cast<bf16x8*>(&Wk[row*40 + c]) = v;
    }
    __syncthreads();

    bf16x8 sv[3];
#define S_LOAD(c0v, ncv) { \
    _Pragma("unroll") \
    for (int k=0;k<3;k++){ \
      int idx = t + k*512; \
      sv[k] = zero_bf8(); \
      if (idx < (ncv)*192){ \
        int d = idx/192, r192 = idx - d*192; \
        int row = r192>>2, c = (r192&3)<<3; \
        int yy = y + (c0v) + d - 7; \
        if (yy>=0 && yy<45 && row<45) \
          sv[k] = *reinterpret_cast<const bf16x8*>(&Qp[(size_t)((yy*45+row)*2+b)*256 + h*32 + c]); \
      } } }
#define S_WRITE(c0v, ncv) { \
    _Pragma("unroll") \
    for (int k=0;k<3;k++){ \
      int idx = t + k*512; \
      if (idx < (ncv)*192){ \
        int d = idx/192, r192 = idx - d*192; \
        int row = r192>>2, c = (r192&3)<<3; \
        int yy = y + (c0v) + d - 7; \
        if (yy>=0 && yy<45) \
          *reinterpret_cast<bf16x8*>(&Wk[d*1920 + row*40 + c]) = sv[k]; \
      } } }

    S_LOAD(0, 6)

    // ---- R pass ----
    for (int fo=w; fo<15; fo+=8){
      bf16x8 wb = *reinterpret_cast<const bf16x8*>(&Wk[(16*fo+lr)*40 + lg*8]);
      int o = 16*fo + lr;
      int dyo = o/15, dxo = o - dyo*15;
      int yyo = y + dyo - 7;
      bool ovalid = (o < 225) && (yyo >= 0) && (yyo < 45);
      float bb = ovalid ? brel_g[h*225+o]*LOG2E : 0.f;
      #pragma unroll
      for (int fa=0; fa<3; fa++){
        bf16x8 qa = *reinterpret_cast<const bf16x8*>(&Qs[(16*fa+lr)*40 + lg*8]);
        f32x4 rr = __builtin_amdgcn_mfma_f32_16x16x32_bf16(qa, wb, zero4, 0, 0, 0);
        if (ovalid){
          #pragma unroll
          for (int r=0;r<4;r++){
            int px = 16*fa + lg*4 + r;
            int xx = px + dxo - 7;
            if (px < 45 && xx >= 0 && xx < 45)
              scb[px*226 + o] = bf16_rne(rr[r] + bb);
          }
        }
      }
    }

    // ---- S pass: 3 chunks ----
    for (int ci=0; ci<3; ci++){
      int c0 = ci*6;
      int nc = (ci<2) ? 6 : 3;
      __syncthreads();
      S_WRITE(c0, nc)
      __syncthreads();
      if (ci==0) S_LOAD(6, 6)
      if (ci==1) S_LOAD(12, 3)
      for (int u=w; u<nc*7; u+=8){
        int d = u/7, pi = u - d*7;
        int dy = c0 + d, yy = y + dy - 7;
        if (yy < 0 || yy >= 45) continue;
        int fa = (0x2110210u >> (4*pi)) & 7;
        int fb = (0x1201210u >> (4*pi)) & 7;
        bf16x8 qa = *reinterpret_cast<const bf16x8*>(&Qs[(16*fa+lr)*40 + lg*8]);
        bf16x8 kb = *reinterpret_cast<const bf16x8*>(&Wk[d*1920 + (16*fb+lr)*40 + lg*8]);
        f32x4 s = __builtin_amdgcn_mfma_f32_16x16x32_bf16(qa, kb, zero4, 0, 0, 0);
        int xx = 16*fb + lr;
        #pragma unroll
        for (int r=0;r<4;r++){
          int px = 16*fa + lg*4 + r;
          int dx = xx - px + 7;
          if (px < 45 && xx < 45 && dx >= 0 && dx < 15){
            int o = dy*15+dx;
            scb[px*226 + o] = bf16_rne(bf2f(scb[px*226 + o]) + s[r]);
          }
        }
      }
    }
    __syncthreads();

    // ---- static softmax (native exp2) ----
    {
      int grp2 = t>>5, lane = t&31;
      for (int px = grp2; px < 45; px += 16){
        float sum = 0.f;
        for (int o=lane; o<225; o+=32){
          float p = fexp2(bf2f(scb[px*226 + o]));
          scb[px*226 + o] = bf16_rne(p);
          sum += p;
        }
        #pragma unroll
        for (int off=16; off>0; off>>=1) sum += __shfl_xor(sum, off);
        float inv = 1.f/sum;
        for (int o=lane; o<225; o+=32)
          scb[px*226 + o] = bf16_rne(bf2f(scb[px*226 + o]) * inv);
      }
    }

    // ---- phase C: per-dy MFMA aggregation ----
    f32x4 acc[3];
    #pragma unroll
    for (int i=0;i<3;i++) acc[i]=(f32x4){0.f,0.f,0.f,0.f};

    const int dyLo = (y < 7) ? (7-y) : 0;
    const int dyHi = (y > 37) ? (51-y) : 14;
    const int kp = t&31, vg = (t>>5)&7, vs = t>>8;
    const int rb0 = vg*16 + vs*8;
    uint4 vA0=z4, vC0=z4;

#define V_LOAD(dyv) { \
      int yy = y + (dyv) - 7; \
      int xx0 = kp*2 - 7, xx1 = xx0 + 1; \
      const uint4* v0p = reinterpret_cast<const uint4*>(Vp + ((size_t)((yy*45+xx0)*2+b))*1024 + h*128 + rb0); \
      const uint4* v1p = reinterpret_cast<const uint4*>(Vp + ((size_t)((yy*45+xx1)*2+b))*1024 + h*128 + rb0); \
      vA0=z4; vC0=z4; \
      if (xx0 >= 0 && xx0 < 45) vA0 = v0p[0]; \
      if (xx1 >= 0 && xx1 < 45) vC0 = v1p[0]; }

    V_LOAD(dyLo)

    for (int dy=dyLo; dy<=dyHi; dy++){
      __syncthreads();

      { // build P~
        unsigned* A32 = (unsigned*)Abuf;
        for (int i=t; i<48*32; i+=512){
          int px = i>>5, wd = i&31;
          int kk0 = wd*2, kk1 = kk0+1;
          unsigned p0 = 0, p1 = 0;
          if (px < 45){
            int dx0 = kk0 - px, dx1 = kk1 - px;
            if (dx0 >= 0 && dx0 < 15 && kk0 >= 7 && kk0 < 52) p0 = scb[px*226 + dy*15+dx0];
            if (dx1 >= 0 && dx1 < 15 && kk1 >= 7 && kk1 < 52) p1 = scb[px*226 + dy*15+dx1];
          }
          A32[px*36 + wd] = p0 | (p1<<16);
        }
      }
      { // stage V^
        unsigned* dst = &Vt2L[rb0*36 + kp];
        VPACK2(dst, 36, 0, vA0.x, vC0.x)
        VPACK2(dst, 36, 2, vA0.y, vC0.y)
        VPACK2(dst, 36, 4, vA0.z, vC0.z)
        VPACK2(dst, 36, 6, vA0.w, vC0.w)
      }
      __syncthreads();

      if (dy < dyHi) V_LOAD(dy+1)

      __builtin_amdgcn_s_setprio(1);
      #pragma unroll
      for (int k3=0; k3<3; k3++){
        int u = w + 8*k3;
        int fa = u>>3, ef = u&7;
        bf16x8 a0 = *reinterpret_cast<const bf16x8*>(&Abuf[(16*fa+lr)*72 + 0*32 + lg*8]);
        bf16x8 b0 = *reinterpret_cast<const bf16x8*>(&Vt2L[(ef*16+lr)*36 + 0*16 + lg*4]);
        acc[k3] = __builtin_amdgcn_mfma_f32_16x16x32_bf16(a0, b0, acc[k3], 0,0,0);
        bf16x8 a1 = *reinterpret_cast<const bf16x8*>(&Abuf[(16*fa+lr)*72 + 1*32 + lg*8]);
        bf16x8 b1 = *reinterpret_cast<const bf16x8*>(&Vt2L[(ef*16+lr)*36 + 1*16 + lg*4]);
        acc[k3] = __builtin_amdgcn_mfma_f32_16x16x32_bf16(a1, b1, acc[k3], 0,0,0);
      }
      __builtin_amdgcn_s_setprio(0);
    }

    // ---- epilogue ----
    #pragma unroll
    for (int k3=0; k3<3; k3++){
      int u = w + 8*k3;
      int fa = u>>3, ef = u&7;
      #pragma unroll
      for (int r=0;r<4;r++){
        int px = 16*fa + lg*4 + r;
        if (px >= 45) continue;
        int e = ef*16 + lr;
        int n = y*45 + px;
        size_t rb = (size_t)(n*2+b);
        int ch = h*128 + e;
        float v = acc[k3][r];
        if (ch < 512) v *= bf2f(Ug[rb*512 + ch]);
        OutL[rb*ldo + ch] = bf16_rne(v);
      }
    }
#undef S_LOAD
#undef S_WRITE
#undef V_LOAD
  }
}

extern "C" void kernel_launch(void* const* d_in, const int* in_sizes, int n_in,
                              void* d_out, int out_size, void* d_ws, size_t ws_size,
                              hipStream_t stream)
{
  const float* tgt    = (const float*)d_in[0];
  const float* id_emb = (const float*)d_in[1];
  const float* ln1_g  = (const float*)d_in[2];
  const float* ln1_b  = (const float*)d_in[3];
  const float* W_qv   = (const float*)d_in[4];
  const float* b_qv   = (const float*)d_in[5];
  const float* W_u    = (const float*)d_in[6];
  const float* b_u    = (const float*)d_in[7];
  const float* W_idv  = (const float*)d_in[8];
  const float* b_idv  = (const float*)d_in[9];
  const float* lt_Wo  = (const float*)d_in[10];
  const float* lt_bo  = (const float*)d_in[11];
  const float* Wrel   = (const float*)d_in[12];
  const float* brel   = (const float*)d_in[13];
  const float* st_Wo  = (const float*)d_in[14];
  const float* st_bo  = (const float*)d_in[15];
  const float* ln2_g  = (const float*)d_in[16];
  const float* ln2_b  = (const float*)d_in[17];
  const float* idln2_g= (const float*)d_in[18];
  const float* idln2_b= (const float*)d_in[19];
  const float* sa_Wqk = (const float*)d_in[20];
  const float* sa_bqk = (const float*)d_in[21];
  const float* sa_Wv  = (const float*)d_in[22];
  const float* sa_bv  = (const float*)d_in[23];
  const float* sa_Wu  = (const float*)d_in[24];
  const float* sa_bu  = (const float*)d_in[25];
  const float* sa_Wo  = (const float*)d_in[26];
  const float* sa_bo  = (const float*)d_in[27];
  float* out = (float*)d_out;
  float* ws  = (float*)d_ws;

  // ---- workspace carving (float units) ----
  float* newt  = ws;                                          // f32 4050x256
  float* tgtid = ws + 1036800;                                // f32 4050x256
  unsigned short* tgt_ln = (unsigned short*)(ws + 2073600);   // bf16 4050x256
  unsigned short* Qbuf   = (unsigned short*)(ws + 2592000);   // bf16 4050x256
  unsigned short* Vbuf   = (unsigned short*)(ws + 3110400);   // bf16 4050x1024
  unsigned short* Ubuf   = (unsigned short*)(ws + 5184000);   // bf16 4050x512
  unsigned short* Gbig   = (unsigned short*)(ws + 6220800);   // bf16 4050x2048
  unsigned short* Us2    = (unsigned short*)(ws + 10368000);  // bf16 4050x1024
  unsigned short* xbuf   = (unsigned short*)(ws + 12441600);  // bf16 4050x512
  unsigned*       Wpk    = (unsigned*)(ws + 13478400);        // 1,605,632 u32
  unsigned short* WrelBf = (unsigned short*)(ws + 15084032);  // 57,600 u16
  unsigned short* idBf   = (unsigned short*)(ws + 15112832);  // 1,036,800 u16

  const unsigned* Wcat1   = Wpk;             // [128][1280]
  const unsigned* Widv_pk = Wpk + 163840;    // [128][512]
  const unsigned* WcatT23 = Wpk + 229376;    // [1024][512]
  const unsigned* Wcat2   = Wpk + 753664;    // [256][2304]
  const unsigned* WsaWo   = Wpk + 1343488;   // [512][512]

  const int M = NBS;
  dim3 blk(256);
  int gx = (M+63)/64;   // 64

  convert_kernel<<<10547, blk, 0, stream>>>(W_qv, W_u, W_idv, lt_Wo, st_Wo,
      sa_Wqk, sa_Wv, sa_Wu, sa_Wo, Wrel, id_emb, (unsigned*)Wpk, WrelBf, idBf);

  ln256_kernel<<<M, 256, 0, stream>>>(tgt, ln1_g, ln1_b, tgt_ln);

  gemm_mfma_kernel<1><<<dim3(gx, 20), blk, 0, stream>>>(
      tgt_ln,256, Wcat1,1280, b_qv, b_u, nullptr, Qbuf, Vbuf, Ubuf, M, 256);
  gemm_mfma_kernel<0><<<dim3(gx, 8), blk, 0, stream>>>(
      idBf,256, Widv_pk,512, b_idv, nullptr, nullptr, Vbuf, nullptr, nullptr, M, 256);

  // fused flash#1 + local, roles interleaved in physical bid space
  attn_fused_kernel<<<dim3(1232), dim3(512), 0, stream>>>(
      Qbuf, Vbuf, Ubuf, Gbig, 512, 2048, WrelBf, brel, Gbig+1024);

  gemm_mfma_kernel<3><<<dim3(gx, 8), blk, 0, stream>>>(
      Gbig,2048, WcatT23,512, lt_bo, st_bo, nullptr, newt, tgtid, (void*)tgt, M, 2048);

  ln_dual_kernel<<<M, 256, 0, stream>>>(newt, tgtid, ln2_g, ln2_b, idln2_g, idln2_b, xbuf);

  gemm_mfma_kernel<2><<<dim3(gx, 36), blk, 0, stream>>>(
      xbuf,512, Wcat2,2304, sa_bqk, sa_bv, sa_bu, Qbuf, Vbuf, Us2, M, 512);

  // flash#2 only (512 blocks, identity map)
  attn_fused_kernel<<<dim3(512), dim3(512), 0, stream>>>(
      Qbuf, Vbuf, Us2, Gbig, 1024, 2048, WrelBf, brel, Gbig+1024);

  gemm_mfma_kernel<4><<<dim3(gx, 8), blk, 0, stream>>>(
      Gbig,2048, WsaWo,512, sa_bo, nullptr, nullptr, out, newt, tgtid, M, 1024);
}

// Round 24
// 265.467 us; speedup vs baseline: 1.0053x; 1.0053x over previous
//
#include <hip/hip_runtime.h>
#include <math.h>

#define NTOK 2025
#define NBS  4050   // NTOK * BS
#define BSZ  2

typedef __attribute__((ext_vector_type(8))) short bf16x8;
typedef __attribute__((ext_vector_type(4))) float f32x4;

__device__ __forceinline__ float silu_f(float v){ return v / (1.f + __expf(-v)); }

__device__ __forceinline__ unsigned short bf16_rne(float f){
  union { float f; unsigned u; } v; v.f = f;
  unsigned u = v.u;
  return (unsigned short)((u + 0x7FFFu + ((u >> 16) & 1u)) >> 16);
}
__device__ __forceinline__ float bf2f(unsigned short u){
  union { unsigned u; float f; } v; v.u = ((unsigned)u)<<16; return v.f;
}
__device__ __forceinline__ bf16x8 zero_bf8(){
  bf16x8 r;
  #pragma unroll
  for (int j=0;j<8;j++) r[j]=0;
  return r;
}
__device__ __forceinline__ float fexp2(float x){
  float r; asm("v_exp_f32 %0, %1" : "=v"(r) : "v"(x)); return r;
}
__device__ __forceinline__ unsigned cvt_pk_bf16(float lo, float hi){
  unsigned r; asm("v_cvt_pk_bf16_f32 %0, %1, %2" : "=v"(r) : "v"(lo), "v"(hi)); return r;
}

#define QSC 0.5050097642f      /* 32^(-1/4) * sqrt(log2 e): QK product carries log2e/sqrt(32) */
#define LOG2E 1.4426950408889634f

#define VPACK2(dst, stride, e0, aw, cw) \
  (dst)[(e0)*(stride)]     = ((aw) & 0xffffu) | ((cw) << 16); \
  (dst)[((e0)+1)*(stride)] = ((aw) >> 16)     | ((cw) & 0xffff0000u);

// ---------------- prologue convert ----------------
__global__ __launch_bounds__(256) void convert_kernel(
    const float* __restrict__ Wqv, const float* __restrict__ Wu, const float* __restrict__ Widv,
    const float* __restrict__ ltWo, const float* __restrict__ stWo, const float* __restrict__ saWqk,
    const float* __restrict__ saWv, const float* __restrict__ saWu, const float* __restrict__ saWo,
    const float* __restrict__ Wrel, const float* __restrict__ idemb,
    unsigned* __restrict__ outPk, unsigned short* __restrict__ outWrel, unsigned short* __restrict__ outId)
{
  int idx = blockIdx.x*256 + threadIdx.x;
  if (idx < 1605632){
    float lo, hi;
    if (idx < 163840){
      int k2 = idx/1280, n = idx - k2*1280;
      const float* W; int ldw, nn;
      if (n < 768){ W=Wqv; ldw=768; nn=n; } else { W=Wu; ldw=512; nn=n-768; }
      lo = W[(size_t)(2*k2)*ldw + nn]; hi = W[(size_t)(2*k2+1)*ldw + nn];
    } else if (idx < 229376){
      int rel = idx-163840; int k2 = rel>>9, n = rel&511;
      lo = Widv[(size_t)(2*k2)*512 + n]; hi = Widv[(size_t)(2*k2+1)*512 + n];
    } else if (idx < 753664){
      int rel = idx-229376; int k2 = rel>>9, n = rel&511;
      int kk = 2*k2;
      if (kk < 1024){ lo = ltWo[(size_t)kk*512 + n]; hi = ltWo[(size_t)(kk+1)*512 + n]; }
      else          { lo = stWo[(size_t)(kk-1024)*512 + n]; hi = stWo[(size_t)(kk-1023)*512 + n]; }
    } else if (idx < 1343488){
      int rel = idx-753664; int k2 = rel/2304, n = rel - k2*2304;
      const float* W; int ldw, nn;
      if (n < 256){ W=saWqk; ldw=256; nn=n; }
      else if (n < 1280){ W=saWv; ldw=1024; nn=n-256; }
      else { W=saWu; ldw=1024; nn=n-1280; }
      lo = W[(size_t)(2*k2)*ldw + nn]; hi = W[(size_t)(2*k2+1)*ldw + nn];
    } else {
      int rel = idx-1343488; int k2 = rel>>9, n = rel&511;
      lo = saWo[(size_t)(2*k2)*512 + n]; hi = saWo[(size_t)(2*k2+1)*512 + n];
    }
    outPk[idx] = (unsigned)bf16_rne(lo) | ((unsigned)bf16_rne(hi)<<16);
  } else if (idx < 1663232){
    int r = idx - 1605632;
    outWrel[r] = bf16_rne(Wrel[r] * QSC);
  } else if (idx < 2700032){
    int r = idx - 1663232;
    outId[r] = bf16_rne(idemb[r]);
  }
}

// ---------------- LayerNorm over C=256, bf16 out ----------------
__global__ __launch_bounds__(256) void ln256_kernel(
    const float* __restrict__ in, const float* __restrict__ g,
    const float* __restrict__ bta, unsigned short* __restrict__ out)
{
  int row = blockIdx.x;
  int t = threadIdx.x;
  float x = in[(size_t)row*256 + t];
  float s = x, s2 = x*x;
  #pragma unroll
  for (int o=32; o>0; o>>=1){ s += __shfl_xor(s,o); s2 += __shfl_xor(s2,o); }
  __shared__ float w1[4], w2[4];
  __shared__ float mean_s, rstd_s;
  int wid = t>>6, lane = t&63;
  if (lane==0){ w1[wid]=s; w2[wid]=s2; }
  __syncthreads();
  if (t==0){
    float S  = w1[0]+w1[1]+w1[2]+w1[3];
    float S2 = w2[0]+w2[1]+w2[2]+w2[3];
    float m = S*(1.f/256.f);
    float v = S2*(1.f/256.f) - m*m;
    mean_s = m; rstd_s = rsqrtf(v + 1e-5f);
  }
  __syncthreads();
  out[(size_t)row*256 + t] = bf16_rne((x-mean_s)*rstd_s*g[t] + bta[t]);
}

// ---------------- dual LayerNorm ----------------
__global__ __launch_bounds__(256) void ln_dual_kernel(
    const float* __restrict__ newt, const float* __restrict__ tgtid,
    const float* __restrict__ g1, const float* __restrict__ b1,
    const float* __restrict__ g2, const float* __restrict__ b2,
    unsigned short* __restrict__ xbuf)
{
  int row = blockIdx.x;
  int t = threadIdx.x;
  float x1 = newt[(size_t)row*256 + t];
  float x2 = tgtid[(size_t)row*256 + t];
  float s1=x1, q1=x1*x1, s2v=x2, q2=x2*x2;
  #pragma unroll
  for (int o=32; o>0; o>>=1){
    s1 += __shfl_xor(s1,o); q1 += __shfl_xor(q1,o);
    s2v += __shfl_xor(s2v,o); q2 += __shfl_xor(q2,o);
  }
  __shared__ float w[4][4];
  __shared__ float st[4];
  int wid = t>>6, lane = t&63;
  if (lane==0){ w[wid][0]=s1; w[wid][1]=q1; w[wid][2]=s2v; w[wid][3]=q2; }
  __syncthreads();
  if (t==0){
    float S1=0,Q1=0,S2=0,Q2=0;
    #pragma unroll
    for (int i=0;i<4;i++){ S1+=w[i][0]; Q1+=w[i][1]; S2+=w[i][2]; Q2+=w[i][3]; }
    float m1=S1*(1.f/256.f), v1=Q1*(1.f/256.f)-m1*m1;
    float m2=S2*(1.f/256.f), v2=Q2*(1.f/256.f)-m2*m2;
    st[0]=m1; st[1]=rsqrtf(v1+1e-5f); st[2]=m2; st[3]=rsqrtf(v2+1e-5f);
  }
  __syncthreads();
  xbuf[(size_t)row*512 + t]       = bf16_rne((x1-st[0])*st[1]*g1[t] + b1[t]);
  xbuf[(size_t)row*512 + 256 + t] = bf16_rne((x2-st[2])*st[3]*g2[t] + b2[t]);
}

// ---------------- MFMA bf16 GEMM, BK=64, fused routing epilogues ----------------
template<int ROUTE>
__global__ __launch_bounds__(256) void gemm_mfma_kernel(
    const unsigned short* __restrict__ A, int lda,
    const unsigned* __restrict__ Bpk, int ldn,
    const float* __restrict__ bias0, const float* __restrict__ bias1, const float* __restrict__ bias2,
    void* __restrict__ P0, void* __restrict__ P1, void* __restrict__ P2,
    int M, int K)
{
  __shared__ __align__(16) unsigned short As[2*64*40];
  __shared__ __align__(16) unsigned Bst[2*64*20];
  const int t = threadIdx.x;
  const int w = t>>6, l = t&63, lr = l&15, lg = l>>4;
  const int m0 = blockIdx.x*64, n0 = blockIdx.y*64;

  const int ar = t>>2,  ak  = (t&3)<<3;
  const int bc = t&63,  bk4 = (t>>6)<<2;

  f32x4 acc[4];
  #pragma unroll
  for (int i=0;i<4;i++) acc[i]=(f32x4){0.f,0.f,0.f,0.f};

  bf16x8 aR0 = zero_bf8(), aR1 = zero_bf8();
  unsigned bR[8];
  {
    if (m0+ar < M){
      aR0 = *reinterpret_cast<const bf16x8*>(&A[(size_t)(m0+ar)*lda + ak]);
      aR1 = *reinterpret_cast<const bf16x8*>(&A[(size_t)(m0+ar)*lda + 32 + ak]);
    }
    #pragma unroll
    for (int j=0;j<4;j++){
      bR[j]   = Bpk[(size_t)(bk4+j)*ldn + n0 + bc];
      bR[4+j] = Bpk[(size_t)(16+bk4+j)*ldn + n0 + bc];
    }
  }

  const int NR = K>>6;
  for (int rr=0; rr<NR; rr++){
    __syncthreads();
    {
      *reinterpret_cast<bf16x8*>(&As[0*2560 + ar*40 + ak]) = aR0;
      *reinterpret_cast<bf16x8*>(&As[1*2560 + ar*40 + ak]) = aR1;
      *reinterpret_cast<uint4*>(&Bst[0*1280 + bc*20 + bk4]) = make_uint4(bR[0],bR[1],bR[2],bR[3]);
      *reinterpret_cast<uint4*>(&Bst[1*1280 + bc*20 + bk4]) = make_uint4(bR[4],bR[5],bR[6],bR[7]);
    }
    __syncthreads();
    if (rr+1 < NR){
      int k0 = (rr+1)<<6;
      if (m0+ar < M){
        aR0 = *reinterpret_cast<const bf16x8*>(&A[(size_t)(m0+ar)*lda + k0 + ak]);
        aR1 = *reinterpret_cast<const bf16x8*>(&A[(size_t)(m0+ar)*lda + k0 + 32 + ak]);
      }
      #pragma unroll
      for (int j=0;j<4;j++){
        bR[j]   = Bpk[(size_t)((k0>>1)+bk4+j)*ldn + n0 + bc];
        bR[4+j] = Bpk[(size_t)((k0>>1)+16+bk4+j)*ldn + n0 + bc];
      }
    }
    bf16x8 af0 = *reinterpret_cast<const bf16x8*>(&As[0*2560 + (w*16+lr)*40 + lg*8]);
    #pragma unroll
    for (int cf=0; cf<4; cf++){
      bf16x8 bf = *reinterpret_cast<const bf16x8*>(&Bst[0*1280 + (cf*16+lr)*20 + lg*4]);
      acc[cf] = __builtin_amdgcn_mfma_f32_16x16x32_bf16(af0, bf, acc[cf], 0,0,0);
    }
    bf16x8 af1 = *reinterpret_cast<const bf16x8*>(&As[1*2560 + (w*16+lr)*40 + lg*8]);
    #pragma unroll
    for (int cf=0; cf<4; cf++){
      bf16x8 bf = *reinterpret_cast<const bf16x8*>(&Bst[1*1280 + (cf*16+lr)*20 + lg*4]);
      acc[cf] = __builtin_amdgcn_mfma_f32_16x16x32_bf16(af1, bf, acc[cf], 0,0,0);
    }
  }

  #pragma unroll
  for (int cf=0; cf<4; cf++){
    int col = n0 + cf*16 + lr;
    float bb;
    if (ROUTE==0) bb = bias0[col];
    if (ROUTE==1) bb = (col<768) ? bias0[col] : bias1[col-768];
    if (ROUTE==2) bb = (col<256) ? bias0[col] : (col<1280 ? bias1[col-256] : bias2[col-1280]);
    if (ROUTE==3) bb = bias0[col] + bias1[col];
    if (ROUTE==4) bb = bias0[col];
    #pragma unroll
    for (int r=0;r<4;r++){
      int row = m0 + w*16 + lg*4 + r;
      if (row >= M) continue;
      float v = acc[cf][r] + bb;
      if (ROUTE==0){
        ((unsigned short*)P0)[(size_t)row*1024 + 512 + col] = bf16_rne(silu_f(v));
      }
      if (ROUTE==1){
        if (col < 256)      ((unsigned short*)P0)[(size_t)row*256 + col] = bf16_rne(v*QSC);
        else if (col < 768) ((unsigned short*)P1)[(size_t)row*1024 + col-256] = bf16_rne(silu_f(v));
        else                ((unsigned short*)P2)[(size_t)row*512 + col-768] = bf16_rne(silu_f(v));
      }
      if (ROUTE==2){
        if (col < 256)       ((unsigned short*)P0)[(size_t)row*256 + col] = bf16_rne(v*QSC);
        else if (col < 1280) ((unsigned short*)P1)[(size_t)row*1024 + col-256] = bf16_rne(silu_f(v));
        else                 ((unsigned short*)P2)[(size_t)row*1024 + col-1280] = bf16_rne(silu_f(v));
      }
      if (ROUTE==3){
        if (col < 256) ((float*)P0)[(size_t)row*256 + col] = v + ((const float*)P2)[(size_t)row*256 + col];
        else           ((float*)P1)[(size_t)row*256 + col-256] = v;
      }
      if (ROUTE==4){
        if (col < 256) ((float*)P0)[(size_t)row*256 + col] = v + ((const float*)P1)[(size_t)row*256 + col];
        else           ((float*)P0)[(size_t)NBS*256 + (size_t)row*256 + col-256] = v + ((const float*)P2)[(size_t)row*256 + col-256];
      }
    }
  }
}

// ---------------- fused attention: compact-LDS flash (3 blocks/CU) + local (8-wave)
// Round-20 proven flash path (guarded prefetch). Role segments interleaved (XCD-preserving).
__global__ __launch_bounds__(512) void attn_fused_kernel(
    const unsigned short* __restrict__ Qp, const unsigned short* __restrict__ Vp,
    const unsigned short* __restrict__ Ug, unsigned short* __restrict__ OutF,
    int gateW, int ldo,
    const unsigned short* __restrict__ WrelBf, const float* __restrict__ brel_g,
    unsigned short* __restrict__ OutL)
{
  __shared__ __align__(16) unsigned char smem[53248];
  const int t = threadIdx.x;
  const f32x4 zero4 = (f32x4){0.f,0.f,0.f,0.f};
  const uint4 z4 = make_uint4(0,0,0,0);

  int fbid = 0, lbid = 0;
  bool isFlash;
  if (gridDim.x == 512){
    isFlash = true; fbid = blockIdx.x;
  } else {
    int bidx = blockIdx.x;
    if (bidx < 256){ isFlash = true;  fbid = bidx; }
    else if (bidx < 616){ isFlash = false; lbid = bidx - 256; }
    else if (bidx < 872){ isFlash = true;  fbid = bidx - 360; }
    else { isFlash = false; lbid = bidx - 512; }
  }

  if (isFlash){
    // ================= FLASH PATH (round-20) =================
    unsigned short* Ks  = (unsigned short*)smem;           // 2*64*40 u16 = 10240B
    unsigned*       Vt2 = (unsigned*)(smem + 10240);       // 2*128*32 u32 = 32768B
    unsigned short* Pb  = (unsigned short*)(smem + 43008); // 8*16*40 u16 = 10240B

    const int w  = t >> 6;
    const int half = w >> 2;
    const int wl = w & 3;
    const int th = t & 255;
    const int l  = t & 63;
    const int lr = l & 15;
    const int lg = l >> 4;

    const int bid = fbid;
    const int xcd = bid & 7, rrr = bid >> 3;
    const int grp = (rrr >> 5)*8 + xcd;
    const int h = grp >> 1, b = grp & 1;
    const int r0 = (rrr & 31) * 64;

    unsigned short* KsH = &Ks[half*64*40];
    unsigned*       VtH = &Vt2[half*128*32];

    bf16x8 qf = zero_bf8();
    {
      int n = r0 + wl*16 + lr;
      if (n < NTOK) qf = *reinterpret_cast<const bf16x8*>(&Qp[(size_t)(n*2+b)*256 + h*32 + lg*8]);
    }

    f32x4 acc[8];
    #pragma unroll
    for (int i=0;i<8;i++) acc[i] = (f32x4){0.f,0.f,0.f,0.f};
    float lrun = 0.f;

    const int key = th & 63, kdh = th >> 6;
    const int kp  = th & 31, vdh = th >> 5;
    const int ktBase = half*16;

    bf16x8 kReg = zero_bf8();
    uint4 vA0=z4, vA1=z4, vC0=z4, vC1=z4;
    {
      int k0p = ktBase*64;
      int n = k0p + key;
      if (n < NTOK) kReg = *reinterpret_cast<const bf16x8*>(&Qp[(size_t)(n*2+b)*256 + h*32 + kdh*8]);
      int n0i = k0p + kp*2, n1i = n0i + 1;
      const uint4* v0 = reinterpret_cast<const uint4*>(Vp + (size_t)(n0i*2+b)*1024 + h*128 + vdh*16);
      const uint4* v1 = reinterpret_cast<const uint4*>(Vp + (size_t)(n1i*2+b)*1024 + h*128 + vdh*16);
      if (n0i < NTOK){ vA0 = v0[0]; vA1 = v0[1]; }
      if (n1i < NTOK){ vC0 = v1[0]; vC1 = v1[1]; }
    }

    for (int it=0; it<16; it++){
      const int k0 = (ktBase + it)*64;
      __syncthreads();

      *reinterpret_cast<bf16x8*>(&KsH[key*40 + kdh*8]) = kReg;
      { // V tile pack, stride-32 XOR swizzled: col' = kp ^ ((row&7)<<2)
        unsigned* Vb = VtH + (vdh*16)*32;
        #define VP2S(e0, aw, cw) \
          Vb[(e0)*32   + (kp ^ (((e0)&7)<<2))]       = ((aw)&0xffffu) | ((cw)<<16); \
          Vb[((e0)+1)*32 + (kp ^ ((((e0)+1)&7)<<2))] = ((aw)>>16)     | ((cw)&0xffff0000u);
        VP2S(0,  vA0.x, vC0.x)
        VP2S(2,  vA0.y, vC0.y)
        VP2S(4,  vA0.z, vC0.z)
        VP2S(6,  vA0.w, vC0.w)
        VP2S(8,  vA1.x, vC1.x)
        VP2S(10, vA1.y, vC1.y)
        VP2S(12, vA1.z, vC1.z)
        VP2S(14, vA1.w, vC1.w)
        #undef VP2S
      }
      __syncthreads();

      if (it+1 < 16){
        int k0n = k0 + 64;
        int n = k0n + key;
        kReg = zero_bf8();
        if (n < NTOK) kReg = *reinterpret_cast<const bf16x8*>(&Qp[(size_t)(n*2+b)*256 + h*32 + kdh*8]);
        int n0i = k0n + kp*2, n1i = n0i + 1;
        const uint4* v0 = reinterpret_cast<const uint4*>(Vp + (size_t)(n0i*2+b)*1024 + h*128 + vdh*16);
        const uint4* v1 = reinterpret_cast<const uint4*>(Vp + (size_t)(n1i*2+b)*1024 + h*128 + vdh*16);
        vA0=z4; vA1=z4; vC0=z4; vC1=z4;
        if (n0i < NTOK){ vA0 = v0[0]; vA1 = v0[1]; }
        if (n1i < NTOK){ vC0 = v1[0]; vC1 = v1[1]; }
      }

      // swapped QK^T: s[f][r] = S[q=lr][key=k0+16f+4lg+r]
      f32x4 s[4];
      #pragma unroll
      for (int f=0;f<4;f++){
        bf16x8 kb = *reinterpret_cast<const bf16x8*>(&KsH[(16*f + lr)*40 + lg*8]);
        s[f] = __builtin_amdgcn_mfma_f32_16x16x32_bf16(kb, qf, zero4, 0, 0, 0);
      }
      #pragma unroll
      for (int f=0;f<4;f++)
        #pragma unroll
        for (int r=0;r<4;r++)
          s[f][r] = fexp2(s[f][r]);
      if (k0 + 64 > NTOK){
        #pragma unroll
        for (int f=0;f<4;f++)
          #pragma unroll
          for (int r=0;r<4;r++)
            if (k0 + 16*f + 4*lg + r >= NTOK) s[f][r] = 0.f;
      }

      { // lane-local row sum + 2 shfl
        float ps = 0.f;
        #pragma unroll
        for (int f=0;f<4;f++){
          ps += s[f][0]; ps += s[f][1]; ps += s[f][2]; ps += s[f][3];
        }
        ps += __shfl_xor(ps, 16);
        ps += __shfl_xor(ps, 32);
        lrun += ps;
      }

      unsigned short* pb = &Pb[w*16*40];
      // sub-phase A: keys 0..31 (f=0,1)
      #pragma unroll
      for (int f=0;f<2;f++){
        unsigned w0 = cvt_pk_bf16(s[f][0], s[f][1]);
        unsigned w1 = cvt_pk_bf16(s[f][2], s[f][3]);
        *reinterpret_cast<uint2*>(&pb[lr*40 + 16*f + 4*lg]) = make_uint2(w0, w1);
      }
      {
        bf16x8 pa0 = *reinterpret_cast<const bf16x8*>(&pb[lr*40 + lg*8]);
        #pragma unroll
        for (int c=0;c<8;c++){
          bf16x8 vb0 = *reinterpret_cast<const bf16x8*>(&VtH[(c*16+lr)*32 + ((lg*4) ^ ((lr&7)<<2))]);
          acc[c] = __builtin_amdgcn_mfma_f32_16x16x32_bf16(pa0, vb0, acc[c], 0, 0, 0);
        }
      }
      // sub-phase B: keys 32..63 (f=2,3) reuse strip
      #pragma unroll
      for (int f=2;f<4;f++){
        unsigned w0 = cvt_pk_bf16(s[f][0], s[f][1]);
        unsigned w1 = cvt_pk_bf16(s[f][2], s[f][3]);
        *reinterpret_cast<uint2*>(&pb[lr*40 + 16*(f-2) + 4*lg]) = make_uint2(w0, w1);
      }
      {
        bf16x8 pa1 = *reinterpret_cast<const bf16x8*>(&pb[lr*40 + lg*8]);
        #pragma unroll
        for (int c=0;c<8;c++){
          bf16x8 vb1 = *reinterpret_cast<const bf16x8*>(&VtH[(c*16+lr)*32 + ((16 + lg*4) ^ ((lr&7)<<2))]);
          acc[c] = __builtin_amdgcn_mfma_f32_16x16x32_bf16(pa1, vb1, acc[c], 0, 0, 0);
        }
      }
    }

    // ---- combine halves: plain sums (swizzled exchange) ----
    __syncthreads();
    float* exA = (float*)Vt2;   // 256 slots x 32 f32, col ^ (slot&31)
    float* exM = (float*)Ks;    // 256 slots x 1 f32
    const int slot = wl*64 + l;
    if (half == 1){
      exM[slot] = lrun;
      #pragma unroll
      for (int c=0;c<8;c++)
        #pragma unroll
        for (int r=0;r<4;r++)
          exA[slot*32 + ((c*4+r) ^ (slot&31))] = acc[c][r];
    }
    __syncthreads();
    if (half == 1) return;

    lrun += exM[slot];
    #pragma unroll
    for (int c=0;c<8;c++)
      #pragma unroll
      for (int r=0;r<4;r++)
        acc[c][r] += exA[slot*32 + ((c*4+r) ^ (slot&31))];

    float linv[4];
    #pragma unroll
    for (int r=0;r<4;r++) linv[r] = 1.f / __shfl(lrun, lg*4 + r);

    #pragma unroll
    for (int r=0;r<4;r++){
      int n = r0 + wl*16 + lg*4 + r;
      if (n >= NTOK) continue;
      size_t rb = (size_t)(n*2+b);
      const unsigned short* ugr = Ug + rb*gateW;
      unsigned short* orow = OutF + rb*ldo + h*128;
      #pragma unroll
      for (int c=0;c<8;c++){
        int dv = c*16 + lr;
        int ch = h*128 + dv;
        float v = acc[c][r]*linv[r];
        if (ch < gateW) v *= bf2f(ugr[ch]);
        orow[dv] = bf16_rne(v);
      }
    }
    return;
  }

  // ================= LOCAL PATH (8 waves) =================
  {
    unsigned short* scb = (unsigned short*)smem;           // 45*226 u16 = 20340B
    float* ubuf = (float*)(smem + 20352);
    unsigned short* Qs = (unsigned short*)ubuf;            // [48*40]
    unsigned short* Wk = Qs + 48*40;
    unsigned short* Abuf = (unsigned short*)ubuf;          // phase C P~ [48][72 u16]
    unsigned*       Vt2L = (unsigned*)(ubuf + 1728);       // phase C V^ [128][36]

    const int w = t>>6, l = t&63;
    const int lr = l&15, lg = l>>4;

    const int xcd = lbid & 7, rrr = lbid >> 3;     // rrr in [0,90)
    const int grp = (rrr/45)*8 + xcd;
    const int h = grp >> 1, b = grp & 1;
    const int y = rrr % 45;

    const unsigned short NEGBF = bf16_rne(-1e9f);

    for (int i=t; i<45*226; i+=512) scb[i] = NEGBF;

    for (int idx=t; idx<192; idx+=512){
      int row = idx>>2, c = (idx&3)<<3;
      bf16x8 v = zero_bf8();
      if (row < 45) v = *reinterpret_cast<const bf16x8*>(&Qp[(size_t)((y*45+row)*2+b)*256 + h*32 + c]);
      *reinterpret_cast<bf16x8*>(&Qs[row*40 + c]) = v;
    }
    for (int idx=t; idx<960; idx+=512){
      int row = idx>>2, c = (idx&3)<<3;
      bf16x8 v = zero_bf8();
      if (row < 225) v = *reinterpret_cast<const bf16x8*>(&WrelBf[((size_t)h*225 + row)*32 + c]);
      *reinterpret_cast<bf16x8*>(&Wk[row*40 + c]) = v;
    }
    __syncthreads();

    bf16x8 sv[3];
#define S_LOAD(c0v, ncv) { \
    _Pragma("unroll") \
    for (int k=0;k<3;k++){ \
      int idx = t + k*512; \
      sv[k] = zero_bf8(); \
      if (idx < (ncv)*192){ \
        int d = idx/192, r192 = idx - d*192; \
        int row = r192>>2, c = (r192&3)<<3; \
        int yy = y + (c0v) + d - 7; \
        if (yy>=0 && yy<45 && row<45) \
          sv[k] = *reinterpret_cast<const bf16x8*>(&Qp[(size_t)((yy*45+row)*2+b)*256 + h*32 + c]); \
      } } }
#define S_WRITE(c0v, ncv) { \
    _Pragma("unroll") \
    for (int k=0;k<3;k++){ \
      int idx = t + k*512; \
      if (idx < (ncv)*192){ \
        int d = idx/192, r192 = idx - d*192; \
        int row = r192>>2, c = (r192&3)<<3; \
        int yy = y + (c0v) + d - 7; \
        if (yy>=0 && yy<45) \
          *reinterpret_cast<bf16x8*>(&Wk[d*1920 + row*40 + c]) = sv[k]; \
      } } }

    S_LOAD(0, 6)

    // ---- R pass (8 waves) ----
    for (int fo=w; fo<15; fo+=8){
      bf16x8 wb = *reinterpret_cast<const bf16x8*>(&Wk[(16*fo+lr)*40 + lg*8]);
      int o = 16*fo + lr;
      int dyo = o/15, dxo = o - dyo*15;
      int yyo = y + dyo - 7;
      bool ovalid = (o < 225) && (yyo >= 0) && (yyo < 45);
      float bb = ovalid ? brel_g[h*225+o]*LOG2E : 0.f;
      #pragma unroll
      for (int fa=0; fa<3; fa++){
        bf16x8 qa = *reinterpret_cast<const bf16x8*>(&Qs[(16*fa+lr)*40 + lg*8]);
        f32x4 rr = __builtin_amdgcn_mfma_f32_16x16x32_bf16(qa, wb, zero4, 0, 0, 0);
        if (ovalid){
          #pragma unroll
          for (int r=0;r<4;r++){
            int px = 16*fa + lg*4 + r;
            int xx = px + dxo - 7;
            if (px < 45 && xx >= 0 && xx < 45)
              scb[px*226 + o] = bf16_rne(rr[r] + bb);
          }
        }
      }
    }

    // ---- S pass: 3 chunks (8 waves) ----
    for (int ci=0; ci<3; ci++){
      int c0 = ci*6;
      int nc = (ci<2) ? 6 : 3;
      __syncthreads();
      S_WRITE(c0, nc)
      __syncthreads();
      if (ci==0) S_LOAD(6, 6)
      if (ci==1) S_LOAD(12, 3)
      for (int u=w; u<nc*7; u+=8){
        int d = u/7, pi = u - d*7;
        int dy = c0 + d, yy = y + dy - 7;
        if (yy < 0 || yy >= 45) continue;
        int fa = (0x2110210u >> (4*pi)) & 7;
        int fb = (0x1201210u >> (4*pi)) & 7;
        bf16x8 qa = *reinterpret_cast<const bf16x8*>(&Qs[(16*fa+lr)*40 + lg*8]);
        bf16x8 kb = *reinterpret_cast<const bf16x8*>(&Wk[d*1920 + (16*fb+lr)*40 + lg*8]);
        f32x4 s = __builtin_amdgcn_mfma_f32_16x16x32_bf16(qa, kb, zero4, 0, 0, 0);
        int xx = 16*fb + lr;
        #pragma unroll
        for (int r=0;r<4;r++){
          int px = 16*fa + lg*4 + r;
          int dx = xx - px + 7;
          if (px < 45 && xx < 45 && dx >= 0 && dx < 15){
            int o = dy*15+dx;
            scb[px*226 + o] = bf16_rne(bf2f(scb[px*226 + o]) + s[r]);
          }
        }
      }
    }
    __syncthreads();

    // ---- static softmax (scores carry log2e -> native exp2) ----
    {
      int grp2 = t>>5, lane = t&31;
      for (int px = grp2; px < 45; px += 16){
        float sum = 0.f;
        for (int o=lane; o<225; o+=32){
          float p = fexp2(bf2f(scb[px*226 + o]));
          scb[px*226 + o] = bf16_rne(p);
          sum += p;
        }
        #pragma unroll
        for (int off=16; off>0; off>>=1) sum += __shfl_xor(sum, off);
        float inv = 1.f/sum;
        for (int o=lane; o<225; o+=32)
          scb[px*226 + o] = bf16_rne(bf2f(scb[px*226 + o]) * inv);
      }
    }

    // ---- phase C: per-dy MFMA aggregation (8 waves, 3 accs each) ----
    f32x4 acc[3];
    #pragma unroll
    for (int i=0;i<3;i++) acc[i]=(f32x4){0.f,0.f,0.f,0.f};

    const int dyLo = (y < 7) ? (7-y) : 0;
    const int dyHi = (y > 37) ? (51-y) : 14;
    const int kp = t&31, vg = (t>>5)&7, vs = t>>8;
    const int rb0 = vg*16 + vs*8;
    uint4 vA0=z4, vC0=z4;

#define V_LOAD(dyv) { \
      int yy = y + (dyv) - 7; \
      int xx0 = kp*2 - 7, xx1 = xx0 + 1; \
      const uint4* v0p = reinterpret_cast<const uint4*>(Vp + ((size_t)((yy*45+xx0)*2+b))*1024 + h*128 + rb0); \
      const uint4* v1p = reinterpret_cast<const uint4*>(Vp + ((size_t)((yy*45+xx1)*2+b))*1024 + h*128 + rb0); \
      vA0=z4; vC0=z4; \
      if (xx0 >= 0 && xx0 < 45) vA0 = v0p[0]; \
      if (xx1 >= 0 && xx1 < 45) vC0 = v1p[0]; }

    V_LOAD(dyLo)

    for (int dy=dyLo; dy<=dyHi; dy++){
      __syncthreads();

      { // build P~
        unsigned* A32 = (unsigned*)Abuf;
        for (int i=t; i<48*32; i+=512){
          int px = i>>5, wd = i&31;
          int kk0 = wd*2, kk1 = kk0+1;
          unsigned p0 = 0, p1 = 0;
          if (px < 45){
            int dx0 = kk0 - px, dx1 = kk1 - px;
            if (dx0 >= 0 && dx0 < 15 && kk0 >= 7 && kk0 < 52) p0 = scb[px*226 + dy*15+dx0];
            if (dx1 >= 0 && dx1 < 15 && kk1 >= 7 && kk1 < 52) p1 = scb[px*226 + dy*15+dx1];
          }
          A32[px*36 + wd] = p0 | (p1<<16);
        }
      }
      { // stage V^ (8 rows per thread)
        unsigned* dst = &Vt2L[rb0*36 + kp];
        VPACK2(dst, 36, 0, vA0.x, vC0.x)
        VPACK2(dst, 36, 2, vA0.y, vC0.y)
        VPACK2(dst, 36, 4, vA0.z, vC0.z)
        VPACK2(dst, 36, 6, vA0.w, vC0.w)
      }
      __syncthreads();

      if (dy < dyHi) V_LOAD(dy+1)

      #pragma unroll
      for (int k3=0; k3<3; k3++){
        int u = w + 8*k3;
        int fa = u>>3, ef = u&7;
        bf16x8 a0 = *reinterpret_cast<const bf16x8*>(&Abuf[(16*fa+lr)*72 + 0*32 + lg*8]);
        bf16x8 b0 = *reinterpret_cast<const bf16x8*>(&Vt2L[(ef*16+lr)*36 + 0*16 + lg*4]);
        acc[k3] = __builtin_amdgcn_mfma_f32_16x16x32_bf16(a0, b0, acc[k3], 0,0,0);
        bf16x8 a1 = *reinterpret_cast<const bf16x8*>(&Abuf[(16*fa+lr)*72 + 1*32 + lg*8]);
        bf16x8 b1 = *reinterpret_cast<const bf16x8*>(&Vt2L[(ef*16+lr)*36 + 1*16 + lg*4]);
        acc[k3] = __builtin_amdgcn_mfma_f32_16x16x32_bf16(a1, b1, acc[k3], 0,0,0);
      }
    }

    // ---- epilogue ----
    #pragma unroll
    for (int k3=0; k3<3; k3++){
      int u = w + 8*k3;
      int fa = u>>3, ef = u&7;
      #pragma unroll
      for (int r=0;r<4;r++){
        int px = 16*fa + lg*4 + r;
        if (px >= 45) continue;
        int e = ef*16 + lr;
        int n = y*45 + px;
        size_t rb = (size_t)(n*2+b);
        int ch = h*128 + e;
        float v = acc[k3][r];
        if (ch < 512) v *= bf2f(Ug[rb*512 + ch]);
        OutL[rb*ldo + ch] = bf16_rne(v);
      }
    }
#undef S_LOAD
#undef S_WRITE
#undef V_LOAD
  }
}

extern "C" void kernel_launch(void* const* d_in, const int* in_sizes, int n_in,
                              void* d_out, int out_size, void* d_ws, size_t ws_size,
                              hipStream_t stream)
{
  const float* tgt    = (const float*)d_in[0];
  const float* id_emb = (const float*)d_in[1];
  const float* ln1_g  = (const float*)d_in[2];
  const float* ln1_b  = (const float*)d_in[3];
  const float* W_qv   = (const float*)d_in[4];
  const float* b_qv   = (const float*)d_in[5];
  const float* W_u    = (const float*)d_in[6];
  const float* b_u    = (const float*)d_in[7];
  const float* W_idv  = (const float*)d_in[8];
  const float* b_idv  = (const float*)d_in[9];
  const float* lt_Wo  = (const float*)d_in[10];
  const float* lt_bo  = (const float*)d_in[11];
  const float* Wrel   = (const float*)d_in[12];
  const float* brel   = (const float*)d_in[13];
  const float* st_Wo  = (const float*)d_in[14];
  const float* st_bo  = (const float*)d_in[15];
  const float* ln2_g  = (const float*)d_in[16];
  const float* ln2_b  = (const float*)d_in[17];
  const float* idln2_g= (const float*)d_in[18];
  const float* idln2_b= (const float*)d_in[19];
  const float* sa_Wqk = (const float*)d_in[20];
  const float* sa_bqk = (const float*)d_in[21];
  const float* sa_Wv  = (const float*)d_in[22];
  const float* sa_bv  = (const float*)d_in[23];
  const float* sa_Wu  = (const float*)d_in[24];
  const float* sa_bu  = (const float*)d_in[25];
  const float* sa_Wo  = (const float*)d_in[26];
  const float* sa_bo  = (const float*)d_in[27];
  float* out = (float*)d_out;
  float* ws  = (float*)d_ws;

  // ---- workspace carving (float units) ----
  float* newt  = ws;                                          // f32 4050x256
  float* tgtid = ws + 1036800;                                // f32 4050x256
  unsigned short* tgt_ln = (unsigned short*)(ws + 2073600);   // bf16 4050x256
  unsigned short* Qbuf   = (unsigned short*)(ws + 2592000);   // bf16 4050x256
  unsigned short* Vbuf   = (unsigned short*)(ws + 3110400);   // bf16 4050x1024
  unsigned short* Ubuf   = (unsigned short*)(ws + 5184000);   // bf16 4050x512
  unsigned short* Gbig   = (unsigned short*)(ws + 6220800);   // bf16 4050x2048
  unsigned short* Us2    = (unsigned short*)(ws + 10368000);  // bf16 4050x1024
  unsigned short* xbuf   = (unsigned short*)(ws + 12441600);  // bf16 4050x512
  unsigned*       Wpk    = (unsigned*)(ws + 13478400);        // 1,605,632 u32
  unsigned short* WrelBf = (unsigned short*)(ws + 15084032);  // 57,600 u16
  unsigned short* idBf   = (unsigned short*)(ws + 15112832);  // 1,036,800 u16

  const unsigned* Wcat1   = Wpk;             // [128][1280]
  const unsigned* Widv_pk = Wpk + 163840;    // [128][512]
  const unsigned* WcatT23 = Wpk + 229376;    // [1024][512]
  const unsigned* Wcat2   = Wpk + 753664;    // [256][2304]
  const unsigned* WsaWo   = Wpk + 1343488;   // [512][512]

  const int M = NBS;
  dim3 blk(256);
  int gx = (M+63)/64;   // 64

  convert_kernel<<<10547, blk, 0, stream>>>(W_qv, W_u, W_idv, lt_Wo, st_Wo,
      sa_Wqk, sa_Wv, sa_Wu, sa_Wo, Wrel, id_emb, (unsigned*)Wpk, WrelBf, idBf);

  ln256_kernel<<<M, 256, 0, stream>>>(tgt, ln1_g, ln1_b, tgt_ln);

  gemm_mfma_kernel<1><<<dim3(gx, 20), blk, 0, stream>>>(
      tgt_ln,256, Wcat1,1280, b_qv, b_u, nullptr, Qbuf, Vbuf, Ubuf, M, 256);
  gemm_mfma_kernel<0><<<dim3(gx, 8), blk, 0, stream>>>(
      idBf,256, Widv_pk,512, b_idv, nullptr, nullptr, Vbuf, nullptr, nullptr, M, 256);

  // fused flash#1 + local, roles interleaved in physical bid space
  attn_fused_kernel<<<dim3(1232), dim3(512), 0, stream>>>(
      Qbuf, Vbuf, Ubuf, Gbig, 512, 2048, WrelBf, brel, Gbig+1024);

  gemm_mfma_kernel<3><<<dim3(gx, 8), blk, 0, stream>>>(
      Gbig,2048, WcatT23,512, lt_bo, st_bo, nullptr, newt, tgtid, (void*)tgt, M, 2048);

  ln_dual_kernel<<<M, 256, 0, stream>>>(newt, tgtid, ln2_g, ln2_b, idln2_g, idln2_b, xbuf);

  gemm_mfma_kernel<2><<<dim3(gx, 36), blk, 0, stream>>>(
      xbuf,512, Wcat2,2304, sa_bqk, sa_bv, sa_bu, Qbuf, Vbuf, Us2, M, 512);

  // flash#2 only (512 blocks, identity map)
  attn_fused_kernel<<<dim3(512), dim3(512), 0, stream>>>(
      Qbuf, Vbuf, Us2, Gbig, 1024, 2048, WrelBf, brel, Gbig+1024);

  gemm_mfma_kernel<4><<<dim3(gx, 8), blk, 0, stream>>>(
      Gbig,2048, WsaWo,512, sa_bo, nullptr, nullptr, out, newt, tgtid, M, 1024);
}

// Round 25
// 263.487 us; speedup vs baseline: 1.0129x; 1.0075x over previous
//
#include <hip/hip_runtime.h>
#include <math.h>

#define NTOK 2025
#define NBS  4050   // NTOK * BS
#define BSZ  2

typedef __attribute__((ext_vector_type(8))) short bf16x8;
typedef __attribute__((ext_vector_type(4))) float f32x4;

__device__ __forceinline__ float silu_f(float v){ return v / (1.f + __expf(-v)); }

__device__ __forceinline__ unsigned short bf16_rne(float f){
  union { float f; unsigned u; } v; v.f = f;
  unsigned u = v.u;
  return (unsigned short)((u + 0x7FFFu + ((u >> 16) & 1u)) >> 16);
}
__device__ __forceinline__ float bf2f(unsigned short u){
  union { unsigned u; float f; } v; v.u = ((unsigned)u)<<16; return v.f;
}
__device__ __forceinline__ bf16x8 zero_bf8(){
  bf16x8 r;
  #pragma unroll
  for (int j=0;j<8;j++) r[j]=0;
  return r;
}
__device__ __forceinline__ float fexp2(float x){
  float r; asm("v_exp_f32 %0, %1" : "=v"(r) : "v"(x)); return r;
}
__device__ __forceinline__ unsigned cvt_pk_bf16(float lo, float hi){
  unsigned r; asm("v_cvt_pk_bf16_f32 %0, %1, %2" : "=v"(r) : "v"(lo), "v"(hi)); return r;
}

#define QSC 0.5050097642f      /* 32^(-1/4) * sqrt(log2 e): QK product carries log2e/sqrt(32) */
#define LOG2E 1.4426950408889634f

#define VPACK2(dst, stride, e0, aw, cw) \
  (dst)[(e0)*(stride)]     = ((aw) & 0xffffu) | ((cw) << 16); \
  (dst)[((e0)+1)*(stride)] = ((aw) >> 16)     | ((cw) & 0xffff0000u);

// ---------------- prologue convert + first LayerNorm (merged, independent work) ----------------
__global__ __launch_bounds__(256) void convert_ln_kernel(
    const float* __restrict__ Wqv, const float* __restrict__ Wu, const float* __restrict__ Widv,
    const float* __restrict__ ltWo, const float* __restrict__ stWo, const float* __restrict__ saWqk,
    const float* __restrict__ saWv, const float* __restrict__ saWu, const float* __restrict__ saWo,
    const float* __restrict__ Wrel, const float* __restrict__ idemb,
    unsigned* __restrict__ outPk, unsigned short* __restrict__ outWrel, unsigned short* __restrict__ outId,
    const float* __restrict__ lnin, const float* __restrict__ lng,
    const float* __restrict__ lnb, unsigned short* __restrict__ lnout)
{
  if (blockIdx.x < 10547){
    int idx = blockIdx.x*256 + threadIdx.x;
    if (idx < 1605632){
      float lo, hi;
      if (idx < 163840){
        int k2 = idx/1280, n = idx - k2*1280;
        const float* W; int ldw, nn;
        if (n < 768){ W=Wqv; ldw=768; nn=n; } else { W=Wu; ldw=512; nn=n-768; }
        lo = W[(size_t)(2*k2)*ldw + nn]; hi = W[(size_t)(2*k2+1)*ldw + nn];
      } else if (idx < 229376){
        int rel = idx-163840; int k2 = rel>>9, n = rel&511;
        lo = Widv[(size_t)(2*k2)*512 + n]; hi = Widv[(size_t)(2*k2+1)*512 + n];
      } else if (idx < 753664){
        int rel = idx-229376; int k2 = rel>>9, n = rel&511;
        int kk = 2*k2;
        if (kk < 1024){ lo = ltWo[(size_t)kk*512 + n]; hi = ltWo[(size_t)(kk+1)*512 + n]; }
        else          { lo = stWo[(size_t)(kk-1024)*512 + n]; hi = stWo[(size_t)(kk-1023)*512 + n]; }
      } else if (idx < 1343488){
        int rel = idx-753664; int k2 = rel/2304, n = rel - k2*2304;
        const float* W; int ldw, nn;
        if (n < 256){ W=saWqk; ldw=256; nn=n; }
        else if (n < 1280){ W=saWv; ldw=1024; nn=n-256; }
        else { W=saWu; ldw=1024; nn=n-1280; }
        lo = W[(size_t)(2*k2)*ldw + nn]; hi = W[(size_t)(2*k2+1)*ldw + nn];
      } else {
        int rel = idx-1343488; int k2 = rel>>9, n = rel&511;
        lo = saWo[(size_t)(2*k2)*512 + n]; hi = saWo[(size_t)(2*k2+1)*512 + n];
      }
      outPk[idx] = (unsigned)bf16_rne(lo) | ((unsigned)bf16_rne(hi)<<16);
    } else if (idx < 1663232){
      int r = idx - 1605632;
      outWrel[r] = bf16_rne(Wrel[r] * QSC);
    } else if (idx < 2700032){
      int r = idx - 1663232;
      outId[r] = bf16_rne(idemb[r]);
    }
  } else {
    int row = blockIdx.x - 10547;
    int t = threadIdx.x;
    float x = lnin[(size_t)row*256 + t];
    float s = x, s2 = x*x;
    #pragma unroll
    for (int o=32; o>0; o>>=1){ s += __shfl_xor(s,o); s2 += __shfl_xor(s2,o); }
    __shared__ float w1[4], w2[4];
    __shared__ float mean_s, rstd_s;
    int wid = t>>6, lane = t&63;
    if (lane==0){ w1[wid]=s; w2[wid]=s2; }
    __syncthreads();
    if (t==0){
      float S  = w1[0]+w1[1]+w1[2]+w1[3];
      float S2 = w2[0]+w2[1]+w2[2]+w2[3];
      float m = S*(1.f/256.f);
      float v = S2*(1.f/256.f) - m*m;
      mean_s = m; rstd_s = rsqrtf(v + 1e-5f);
    }
    __syncthreads();
    lnout[(size_t)row*256 + t] = bf16_rne((x-mean_s)*rstd_s*lng[t] + lnb[t]);
  }
}

// ---------------- dual LayerNorm ----------------
__global__ __launch_bounds__(256) void ln_dual_kernel(
    const float* __restrict__ newt, const float* __restrict__ tgtid,
    const float* __restrict__ g1, const float* __restrict__ b1,
    const float* __restrict__ g2, const float* __restrict__ b2,
    unsigned short* __restrict__ xbuf)
{
  int row = blockIdx.x;
  int t = threadIdx.x;
  float x1 = newt[(size_t)row*256 + t];
  float x2 = tgtid[(size_t)row*256 + t];
  float s1=x1, q1=x1*x1, s2v=x2, q2=x2*x2;
  #pragma unroll
  for (int o=32; o>0; o>>=1){
    s1 += __shfl_xor(s1,o); q1 += __shfl_xor(q1,o);
    s2v += __shfl_xor(s2v,o); q2 += __shfl_xor(q2,o);
  }
  __shared__ float w[4][4];
  __shared__ float st[4];
  int wid = t>>6, lane = t&63;
  if (lane==0){ w[wid][0]=s1; w[wid][1]=q1; w[wid][2]=s2v; w[wid][3]=q2; }
  __syncthreads();
  if (t==0){
    float S1=0,Q1=0,S2=0,Q2=0;
    #pragma unroll
    for (int i=0;i<4;i++){ S1+=w[i][0]; Q1+=w[i][1]; S2+=w[i][2]; Q2+=w[i][3]; }
    float m1=S1*(1.f/256.f), v1=Q1*(1.f/256.f)-m1*m1;
    float m2=S2*(1.f/256.f), v2=Q2*(1.f/256.f)-m2*m2;
    st[0]=m1; st[1]=rsqrtf(v1+1e-5f); st[2]=m2; st[3]=rsqrtf(v2+1e-5f);
  }
  __syncthreads();
  xbuf[(size_t)row*512 + t]       = bf16_rne((x1-st[0])*st[1]*g1[t] + b1[t]);
  xbuf[(size_t)row*512 + 256 + t] = bf16_rne((x2-st[2])*st[3]*g2[t] + b2[t]);
}

// ---------------- MFMA bf16 GEMM, BK=64, fused routing epilogues ----------------
template<int ROUTE>
__global__ __launch_bounds__(256) void gemm_mfma_kernel(
    const unsigned short* __restrict__ A, int lda,
    const unsigned* __restrict__ Bpk, int ldn,
    const float* __restrict__ bias0, const float* __restrict__ bias1, const float* __restrict__ bias2,
    void* __restrict__ P0, void* __restrict__ P1, void* __restrict__ P2,
    int M, int K)
{
  __shared__ __align__(16) unsigned short As[2*64*40];
  __shared__ __align__(16) unsigned Bst[2*64*20];
  const int t = threadIdx.x;
  const int w = t>>6, l = t&63, lr = l&15, lg = l>>4;
  const int m0 = blockIdx.x*64, n0 = blockIdx.y*64;

  const int ar = t>>2,  ak  = (t&3)<<3;
  const int bc = t&63,  bk4 = (t>>6)<<2;

  f32x4 acc[4];
  #pragma unroll
  for (int i=0;i<4;i++) acc[i]=(f32x4){0.f,0.f,0.f,0.f};

  bf16x8 aR0 = zero_bf8(), aR1 = zero_bf8();
  unsigned bR[8];
  {
    if (m0+ar < M){
      aR0 = *reinterpret_cast<const bf16x8*>(&A[(size_t)(m0+ar)*lda + ak]);
      aR1 = *reinterpret_cast<const bf16x8*>(&A[(size_t)(m0+ar)*lda + 32 + ak]);
    }
    #pragma unroll
    for (int j=0;j<4;j++){
      bR[j]   = Bpk[(size_t)(bk4+j)*ldn + n0 + bc];
      bR[4+j] = Bpk[(size_t)(16+bk4+j)*ldn + n0 + bc];
    }
  }

  const int NR = K>>6;
  for (int rr=0; rr<NR; rr++){
    __syncthreads();
    {
      *reinterpret_cast<bf16x8*>(&As[0*2560 + ar*40 + ak]) = aR0;
      *reinterpret_cast<bf16x8*>(&As[1*2560 + ar*40 + ak]) = aR1;
      *reinterpret_cast<uint4*>(&Bst[0*1280 + bc*20 + bk4]) = make_uint4(bR[0],bR[1],bR[2],bR[3]);
      *reinterpret_cast<uint4*>(&Bst[1*1280 + bc*20 + bk4]) = make_uint4(bR[4],bR[5],bR[6],bR[7]);
    }
    __syncthreads();
    if (rr+1 < NR){
      int k0 = (rr+1)<<6;
      if (m0+ar < M){
        aR0 = *reinterpret_cast<const bf16x8*>(&A[(size_t)(m0+ar)*lda + k0 + ak]);
        aR1 = *reinterpret_cast<const bf16x8*>(&A[(size_t)(m0+ar)*lda + k0 + 32 + ak]);
      }
      #pragma unroll
      for (int j=0;j<4;j++){
        bR[j]   = Bpk[(size_t)((k0>>1)+bk4+j)*ldn + n0 + bc];
        bR[4+j] = Bpk[(size_t)((k0>>1)+16+bk4+j)*ldn + n0 + bc];
      }
    }
    bf16x8 af0 = *reinterpret_cast<const bf16x8*>(&As[0*2560 + (w*16+lr)*40 + lg*8]);
    #pragma unroll
    for (int cf=0; cf<4; cf++){
      bf16x8 bf = *reinterpret_cast<const bf16x8*>(&Bst[0*1280 + (cf*16+lr)*20 + lg*4]);
      acc[cf] = __builtin_amdgcn_mfma_f32_16x16x32_bf16(af0, bf, acc[cf], 0,0,0);
    }
    bf16x8 af1 = *reinterpret_cast<const bf16x8*>(&As[1*2560 + (w*16+lr)*40 + lg*8]);
    #pragma unroll
    for (int cf=0; cf<4; cf++){
      bf16x8 bf = *reinterpret_cast<const bf16x8*>(&Bst[1*1280 + (cf*16+lr)*20 + lg*4]);
      acc[cf] = __builtin_amdgcn_mfma_f32_16x16x32_bf16(af1, bf, acc[cf], 0,0,0);
    }
  }

  #pragma unroll
  for (int cf=0; cf<4; cf++){
    int col = n0 + cf*16 + lr;
    float bb;
    if (ROUTE==0) bb = bias0[col];
    if (ROUTE==1) bb = (col<768) ? bias0[col] : bias1[col-768];
    if (ROUTE==2) bb = (col<256) ? bias0[col] : (col<1280 ? bias1[col-256] : bias2[col-1280]);
    if (ROUTE==3) bb = bias0[col] + bias1[col];
    if (ROUTE==4) bb = bias0[col];
    #pragma unroll
    for (int r=0;r<4;r++){
      int row = m0 + w*16 + lg*4 + r;
      if (row >= M) continue;
      float v = acc[cf][r] + bb;
      if (ROUTE==0){
        ((unsigned short*)P0)[(size_t)row*1024 + 512 + col] = bf16_rne(silu_f(v));
      }
      if (ROUTE==1){
        if (col < 256)      ((unsigned short*)P0)[(size_t)row*256 + col] = bf16_rne(v*QSC);
        else if (col < 768) ((unsigned short*)P1)[(size_t)row*1024 + col-256] = bf16_rne(silu_f(v));
        else                ((unsigned short*)P2)[(size_t)row*512 + col-768] = bf16_rne(silu_f(v));
      }
      if (ROUTE==2){
        if (col < 256)       ((unsigned short*)P0)[(size_t)row*256 + col] = bf16_rne(v*QSC);
        else if (col < 1280) ((unsigned short*)P1)[(size_t)row*1024 + col-256] = bf16_rne(silu_f(v));
        else                 ((unsigned short*)P2)[(size_t)row*1024 + col-1280] = bf16_rne(silu_f(v));
      }
      if (ROUTE==3){
        if (col < 256) ((float*)P0)[(size_t)row*256 + col] = v + ((const float*)P2)[(size_t)row*256 + col];
        else           ((float*)P1)[(size_t)row*256 + col-256] = v;
      }
      if (ROUTE==4){
        if (col < 256) ((float*)P0)[(size_t)row*256 + col] = v + ((const float*)P1)[(size_t)row*256 + col];
        else           ((float*)P0)[(size_t)NBS*256 + (size_t)row*256 + col-256] = v + ((const float*)P2)[(size_t)row*256 + col-256];
      }
    }
  }
}

// ---------------- fused attention: compact-LDS flash (3 blocks/CU) + local (8-wave)
// Round-20 flash path; lrun cross-lane reduction deferred out of the k-loop.
__global__ __launch_bounds__(512) void attn_fused_kernel(
    const unsigned short* __restrict__ Qp, const unsigned short* __restrict__ Vp,
    const unsigned short* __restrict__ Ug, unsigned short* __restrict__ OutF,
    int gateW, int ldo,
    const unsigned short* __restrict__ WrelBf, const float* __restrict__ brel_g,
    unsigned short* __restrict__ OutL)
{
  __shared__ __align__(16) unsigned char smem[53248];
  const int t = threadIdx.x;
  const f32x4 zero4 = (f32x4){0.f,0.f,0.f,0.f};
  const uint4 z4 = make_uint4(0,0,0,0);

  int fbid = 0, lbid = 0;
  bool isFlash;
  if (gridDim.x == 512){
    isFlash = true; fbid = blockIdx.x;
  } else {
    int bidx = blockIdx.x;
    if (bidx < 256){ isFlash = true;  fbid = bidx; }
    else if (bidx < 616){ isFlash = false; lbid = bidx - 256; }
    else if (bidx < 872){ isFlash = true;  fbid = bidx - 360; }
    else { isFlash = false; lbid = bidx - 512; }
  }

  if (isFlash){
    // ================= FLASH PATH =================
    unsigned short* Ks  = (unsigned short*)smem;           // 2*64*40 u16 = 10240B
    unsigned*       Vt2 = (unsigned*)(smem + 10240);       // 2*128*32 u32 = 32768B
    unsigned short* Pb  = (unsigned short*)(smem + 43008); // 8*16*40 u16 = 10240B

    const int w  = t >> 6;
    const int half = w >> 2;
    const int wl = w & 3;
    const int th = t & 255;
    const int l  = t & 63;
    const int lr = l & 15;
    const int lg = l >> 4;

    const int bid = fbid;
    const int xcd = bid & 7, rrr = bid >> 3;
    const int grp = (rrr >> 5)*8 + xcd;
    const int h = grp >> 1, b = grp & 1;
    const int r0 = (rrr & 31) * 64;

    unsigned short* KsH = &Ks[half*64*40];
    unsigned*       VtH = &Vt2[half*128*32];

    bf16x8 qf = zero_bf8();
    {
      int n = r0 + wl*16 + lr;
      if (n < NTOK) qf = *reinterpret_cast<const bf16x8*>(&Qp[(size_t)(n*2+b)*256 + h*32 + lg*8]);
    }

    f32x4 acc[8];
    #pragma unroll
    for (int i=0;i<8;i++) acc[i] = (f32x4){0.f,0.f,0.f,0.f};
    float lrun = 0.f;

    const int key = th & 63, kdh = th >> 6;
    const int kp  = th & 31, vdh = th >> 5;
    const int ktBase = half*16;

    bf16x8 kReg = zero_bf8();
    uint4 vA0=z4, vA1=z4, vC0=z4, vC1=z4;
    {
      int k0p = ktBase*64;
      int n = k0p + key;
      if (n < NTOK) kReg = *reinterpret_cast<const bf16x8*>(&Qp[(size_t)(n*2+b)*256 + h*32 + kdh*8]);
      int n0i = k0p + kp*2, n1i = n0i + 1;
      const uint4* v0 = reinterpret_cast<const uint4*>(Vp + (size_t)(n0i*2+b)*1024 + h*128 + vdh*16);
      const uint4* v1 = reinterpret_cast<const uint4*>(Vp + (size_t)(n1i*2+b)*1024 + h*128 + vdh*16);
      if (n0i < NTOK){ vA0 = v0[0]; vA1 = v0[1]; }
      if (n1i < NTOK){ vC0 = v1[0]; vC1 = v1[1]; }
    }

    for (int it=0; it<16; it++){
      const int k0 = (ktBase + it)*64;
      __syncthreads();

      *reinterpret_cast<bf16x8*>(&KsH[key*40 + kdh*8]) = kReg;
      { // V tile pack, stride-32 XOR swizzled: col' = kp ^ ((row&7)<<2)
        unsigned* Vb = VtH + (vdh*16)*32;
        #define VP2S(e0, aw, cw) \
          Vb[(e0)*32   + (kp ^ (((e0)&7)<<2))]       = ((aw)&0xffffu) | ((cw)<<16); \
          Vb[((e0)+1)*32 + (kp ^ ((((e0)+1)&7)<<2))] = ((aw)>>16)     | ((cw)&0xffff0000u);
        VP2S(0,  vA0.x, vC0.x)
        VP2S(2,  vA0.y, vC0.y)
        VP2S(4,  vA0.z, vC0.z)
        VP2S(6,  vA0.w, vC0.w)
        VP2S(8,  vA1.x, vC1.x)
        VP2S(10, vA1.y, vC1.y)
        VP2S(12, vA1.z, vC1.z)
        VP2S(14, vA1.w, vC1.w)
        #undef VP2S
      }
      __syncthreads();

      if (it+1 < 16){
        int k0n = k0 + 64;
        int n = k0n + key;
        kReg = zero_bf8();
        if (n < NTOK) kReg = *reinterpret_cast<const bf16x8*>(&Qp[(size_t)(n*2+b)*256 + h*32 + kdh*8]);
        int n0i = k0n + kp*2, n1i = n0i + 1;
        const uint4* v0 = reinterpret_cast<const uint4*>(Vp + (size_t)(n0i*2+b)*1024 + h*128 + vdh*16);
        const uint4* v1 = reinterpret_cast<const uint4*>(Vp + (size_t)(n1i*2+b)*1024 + h*128 + vdh*16);
        vA0=z4; vA1=z4; vC0=z4; vC1=z4;
        if (n0i < NTOK){ vA0 = v0[0]; vA1 = v0[1]; }
        if (n1i < NTOK){ vC0 = v1[0]; vC1 = v1[1]; }
      }

      // swapped QK^T: s[f][r] = S[q=lr][key=k0+16f+4lg+r]
      f32x4 s[4];
      #pragma unroll
      for (int f=0;f<4;f++){
        bf16x8 kb = *reinterpret_cast<const bf16x8*>(&KsH[(16*f + lr)*40 + lg*8]);
        s[f] = __builtin_amdgcn_mfma_f32_16x16x32_bf16(kb, qf, zero4, 0, 0, 0);
      }
      #pragma unroll
      for (int f=0;f<4;f++)
        #pragma unroll
        for (int r=0;r<4;r++)
          s[f][r] = fexp2(s[f][r]);
      if (k0 + 64 > NTOK){
        #pragma unroll
        for (int f=0;f<4;f++)
          #pragma unroll
          for (int r=0;r<4;r++)
            if (k0 + 16*f + 4*lg + r >= NTOK) s[f][r] = 0.f;
      }

      { // lane-local row sum (cross-lane reduce deferred to after the loop)
        float ps = 0.f;
        #pragma unroll
        for (int f=0;f<4;f++){
          ps += s[f][0]; ps += s[f][1]; ps += s[f][2]; ps += s[f][3];
        }
        lrun += ps;
      }

      unsigned short* pb = &Pb[w*16*40];
      // sub-phase A: keys 0..31 (f=0,1)
      #pragma unroll
      for (int f=0;f<2;f++){
        unsigned w0 = cvt_pk_bf16(s[f][0], s[f][1]);
        unsigned w1 = cvt_pk_bf16(s[f][2], s[f][3]);
        *reinterpret_cast<uint2*>(&pb[lr*40 + 16*f + 4*lg]) = make_uint2(w0, w1);
      }
      {
        bf16x8 pa0 = *reinterpret_cast<const bf16x8*>(&pb[lr*40 + lg*8]);
        #pragma unroll
        for (int c=0;c<8;c++){
          bf16x8 vb0 = *reinterpret_cast<const bf16x8*>(&VtH[(c*16+lr)*32 + ((lg*4) ^ ((lr&7)<<2))]);
          acc[c] = __builtin_amdgcn_mfma_f32_16x16x32_bf16(pa0, vb0, acc[c], 0, 0, 0);
        }
      }
      // sub-phase B: keys 32..63 (f=2,3) reuse strip
      #pragma unroll
      for (int f=2;f<4;f++){
        unsigned w0 = cvt_pk_bf16(s[f][0], s[f][1]);
        unsigned w1 = cvt_pk_bf16(s[f][2], s[f][3]);
        *reinterpret_cast<uint2*>(&pb[lr*40 + 16*(f-2) + 4*lg]) = make_uint2(w0, w1);
      }
      {
        bf16x8 pa1 = *reinterpret_cast<const bf16x8*>(&pb[lr*40 + lg*8]);
        #pragma unroll
        for (int c=0;c<8;c++){
          bf16x8 vb1 = *reinterpret_cast<const bf16x8*>(&VtH[(c*16+lr)*32 + ((16 + lg*4) ^ ((lr&7)<<2))]);
          acc[c] = __builtin_amdgcn_mfma_f32_16x16x32_bf16(pa1, vb1, acc[c], 0, 0, 0);
        }
      }
    }

    // deferred cross-lane reduction (sum of shuffles == shuffle of sums)
    lrun += __shfl_xor(lrun, 16);
    lrun += __shfl_xor(lrun, 32);

    // ---- combine halves: plain sums (swizzled exchange) ----
    __syncthreads();
    float* exA = (float*)Vt2;   // 256 slots x 32 f32, col ^ (slot&31)
    float* exM = (float*)Ks;    // 256 slots x 1 f32
    const int slot = wl*64 + l;
    if (half == 1){
      exM[slot] = lrun;
      #pragma unroll
      for (int c=0;c<8;c++)
        #pragma unroll
        for (int r=0;r<4;r++)
          exA[slot*32 + ((c*4+r) ^ (slot&31))] = acc[c][r];
    }
    __syncthreads();
    if (half == 1) return;

    lrun += exM[slot];
    #pragma unroll
    for (int c=0;c<8;c++)
      #pragma unroll
      for (int r=0;r<4;r++)
        acc[c][r] += exA[slot*32 + ((c*4+r) ^ (slot&31))];

    float linv[4];
    #pragma unroll
    for (int r=0;r<4;r++) linv[r] = 1.f / __shfl(lrun, lg*4 + r);

    #pragma unroll
    for (int r=0;r<4;r++){
      int n = r0 + wl*16 + lg*4 + r;
      if (n >= NTOK) continue;
      size_t rb = (size_t)(n*2+b);
      const unsigned short* ugr = Ug + rb*gateW;
      unsigned short* orow = OutF + rb*ldo + h*128;
      #pragma unroll
      for (int c=0;c<8;c++){
        int dv = c*16 + lr;
        int ch = h*128 + dv;
        float v = acc[c][r]*linv[r];
        if (ch < gateW) v *= bf2f(ugr[ch]);
        orow[dv] = bf16_rne(v);
      }
    }
    return;
  }

  // ================= LOCAL PATH (8 waves) =================
  {
    unsigned short* scb = (unsigned short*)smem;           // 45*226 u16 = 20340B
    float* ubuf = (float*)(smem + 20352);
    unsigned short* Qs = (unsigned short*)ubuf;            // [48*40]
    unsigned short* Wk = Qs + 48*40;
    unsigned short* Abuf = (unsigned short*)ubuf;          // phase C P~ [48][72 u16]
    unsigned*       Vt2L = (unsigned*)(ubuf + 1728);       // phase C V^ [128][36]

    const int w = t>>6, l = t&63;
    const int lr = l&15, lg = l>>4;

    const int xcd = lbid & 7, rrr = lbid >> 3;     // rrr in [0,90)
    const int grp = (rrr/45)*8 + xcd;
    const int h = grp >> 1, b = grp & 1;
    const int y = rrr % 45;

    const unsigned short NEGBF = bf16_rne(-1e9f);

    for (int i=t; i<45*226; i+=512) scb[i] = NEGBF;

    for (int idx=t; idx<192; idx+=512){
      int row = idx>>2, c = (idx&3)<<3;
      bf16x8 v = zero_bf8();
      if (row < 45) v = *reinterpret_cast<const bf16x8*>(&Qp[(size_t)((y*45+row)*2+b)*256 + h*32 + c]);
      *reinterpret_cast<bf16x8*>(&Qs[row*40 + c]) = v;
    }
    for (int idx=t; idx<960; idx+=512){
      int row = idx>>2, c = (idx&3)<<3;
      bf16x8 v = zero_bf8();
      if (row < 225) v = *reinterpret_cast<const bf16x8*>(&WrelBf[((size_t)h*225 + row)*32 + c]);
      *reinterpret_cast<bf16x8*>(&Wk[row*40 + c]) = v;
    }
    __syncthreads();

    bf16x8 sv[3];
#define S_LOAD(c0v, ncv) { \
    _Pragma("unroll") \
    for (int k=0;k<3;k++){ \
      int idx = t + k*512; \
      sv[k] = zero_bf8(); \
      if (idx < (ncv)*192){ \
        int d = idx/192, r192 = idx - d*192; \
        int row = r192>>2, c = (r192&3)<<3; \
        int yy = y + (c0v) + d - 7; \
        if (yy>=0 && yy<45 && row<45) \
          sv[k] = *reinterpret_cast<const bf16x8*>(&Qp[(size_t)((yy*45+row)*2+b)*256 + h*32 + c]); \
      } } }
#define S_WRITE(c0v, ncv) { \
    _Pragma("unroll") \
    for (int k=0;k<3;k++){ \
      int idx = t + k*512; \
      if (idx < (ncv)*192){ \
        int d = idx/192, r192 = idx - d*192; \
        int row = r192>>2, c = (r192&3)<<3; \
        int yy = y + (c0v) + d - 7; \
        if (yy>=0 && yy<45) \
          *reinterpret_cast<bf16x8*>(&Wk[d*1920 + row*40 + c]) = sv[k]; \
      } } }

    S_LOAD(0, 6)

    // ---- R pass (8 waves) ----
    for (int fo=w; fo<15; fo+=8){
      bf16x8 wb = *reinterpret_cast<const bf16x8*>(&Wk[(16*fo+lr)*40 + lg*8]);
      int o = 16*fo + lr;
      int dyo = o/15, dxo = o - dyo*15;
      int yyo = y + dyo - 7;
      bool ovalid = (o < 225) && (yyo >= 0) && (yyo < 45);
      float bb = ovalid ? brel_g[h*225+o]*LOG2E : 0.f;
      #pragma unroll
      for (int fa=0; fa<3; fa++){
        bf16x8 qa = *reinterpret_cast<const bf16x8*>(&Qs[(16*fa+lr)*40 + lg*8]);
        f32x4 rr = __builtin_amdgcn_mfma_f32_16x16x32_bf16(qa, wb, zero4, 0, 0, 0);
        if (ovalid){
          #pragma unroll
          for (int r=0;r<4;r++){
            int px = 16*fa + lg*4 + r;
            int xx = px + dxo - 7;
            if (px < 45 && xx >= 0 && xx < 45)
              scb[px*226 + o] = bf16_rne(rr[r] + bb);
          }
        }
      }
    }

    // ---- S pass: 3 chunks (8 waves) ----
    for (int ci=0; ci<3; ci++){
      int c0 = ci*6;
      int nc = (ci<2) ? 6 : 3;
      __syncthreads();
      S_WRITE(c0, nc)
      __syncthreads();
      if (ci==0) S_LOAD(6, 6)
      if (ci==1) S_LOAD(12, 3)
      for (int u=w; u<nc*7; u+=8){
        int d = u/7, pi = u - d*7;
        int dy = c0 + d, yy = y + dy - 7;
        if (yy < 0 || yy >= 45) continue;
        int fa = (0x2110210u >> (4*pi)) & 7;
        int fb = (0x1201210u >> (4*pi)) & 7;
        bf16x8 qa = *reinterpret_cast<const bf16x8*>(&Qs[(16*fa+lr)*40 + lg*8]);
        bf16x8 kb = *reinterpret_cast<const bf16x8*>(&Wk[d*1920 + (16*fb+lr)*40 + lg*8]);
        f32x4 s = __builtin_amdgcn_mfma_f32_16x16x32_bf16(qa, kb, zero4, 0, 0, 0);
        int xx = 16*fb + lr;
        #pragma unroll
        for (int r=0;r<4;r++){
          int px = 16*fa + lg*4 + r;
          int dx = xx - px + 7;
          if (px < 45 && xx < 45 && dx >= 0 && dx < 15){
            int o = dy*15+dx;
            scb[px*226 + o] = bf16_rne(bf2f(scb[px*226 + o]) + s[r]);
          }
        }
      }
    }
    __syncthreads();

    // ---- static softmax (scores carry log2e -> native exp2) ----
    {
      int grp2 = t>>5, lane = t&31;
      for (int px = grp2; px < 45; px += 16){
        float sum = 0.f;
        for (int o=lane; o<225; o+=32){
          float p = fexp2(bf2f(scb[px*226 + o]));
          scb[px*226 + o] = bf16_rne(p);
          sum += p;
        }
        #pragma unroll
        for (int off=16; off>0; off>>=1) sum += __shfl_xor(sum, off);
        float inv = 1.f/sum;
        for (int o=lane; o<225; o+=32)
          scb[px*226 + o] = bf16_rne(bf2f(scb[px*226 + o]) * inv);
      }
    }

    // ---- phase C: per-dy MFMA aggregation (8 waves, 3 accs each) ----
    f32x4 acc[3];
    #pragma unroll
    for (int i=0;i<3;i++) acc[i]=(f32x4){0.f,0.f,0.f,0.f};

    const int dyLo = (y < 7) ? (7-y) : 0;
    const int dyHi = (y > 37) ? (51-y) : 14;
    const int kp = t&31, vg = (t>>5)&7, vs = t>>8;
    const int rb0 = vg*16 + vs*8;
    uint4 vA0=z4, vC0=z4;

#define V_LOAD(dyv) { \
      int yy = y + (dyv) - 7; \
      int xx0 = kp*2 - 7, xx1 = xx0 + 1; \
      const uint4* v0p = reinterpret_cast<const uint4*>(Vp + ((size_t)((yy*45+xx0)*2+b))*1024 + h*128 + rb0); \
      const uint4* v1p = reinterpret_cast<const uint4*>(Vp + ((size_t)((yy*45+xx1)*2+b))*1024 + h*128 + rb0); \
      vA0=z4; vC0=z4; \
      if (xx0 >= 0 && xx0 < 45) vA0 = v0p[0]; \
      if (xx1 >= 0 && xx1 < 45) vC0 = v1p[0]; }

    V_LOAD(dyLo)

    for (int dy=dyLo; dy<=dyHi; dy++){
      __syncthreads();

      { // build P~
        unsigned* A32 = (unsigned*)Abuf;
        for (int i=t; i<48*32; i+=512){
          int px = i>>5, wd = i&31;
          int kk0 = wd*2, kk1 = kk0+1;
          unsigned p0 = 0, p1 = 0;
          if (px < 45){
            int dx0 = kk0 - px, dx1 = kk1 - px;
            if (dx0 >= 0 && dx0 < 15 && kk0 >= 7 && kk0 < 52) p0 = scb[px*226 + dy*15+dx0];
            if (dx1 >= 0 && dx1 < 15 && kk1 >= 7 && kk1 < 52) p1 = scb[px*226 + dy*15+dx1];
          }
          A32[px*36 + wd] = p0 | (p1<<16);
        }
      }
      { // stage V^ (8 rows per thread)
        unsigned* dst = &Vt2L[rb0*36 + kp];
        VPACK2(dst, 36, 0, vA0.x, vC0.x)
        VPACK2(dst, 36, 2, vA0.y, vC0.y)
        VPACK2(dst, 36, 4, vA0.z, vC0.z)
        VPACK2(dst, 36, 6, vA0.w, vC0.w)
      }
      __syncthreads();

      if (dy < dyHi) V_LOAD(dy+1)

      #pragma unroll
      for (int k3=0; k3<3; k3++){
        int u = w + 8*k3;
        int fa = u>>3, ef = u&7;
        bf16x8 a0 = *reinterpret_cast<const bf16x8*>(&Abuf[(16*fa+lr)*72 + 0*32 + lg*8]);
        bf16x8 b0 = *reinterpret_cast<const bf16x8*>(&Vt2L[(ef*16+lr)*36 + 0*16 + lg*4]);
        acc[k3] = __builtin_amdgcn_mfma_f32_16x16x32_bf16(a0, b0, acc[k3], 0,0,0);
        bf16x8 a1 = *reinterpret_cast<const bf16x8*>(&Abuf[(16*fa+lr)*72 + 1*32 + lg*8]);
        bf16x8 b1 = *reinterpret_cast<const bf16x8*>(&Vt2L[(ef*16+lr)*36 + 1*16 + lg*4]);
        acc[k3] = __builtin_amdgcn_mfma_f32_16x16x32_bf16(a1, b1, acc[k3], 0,0,0);
      }
    }

    // ---- epilogue ----
    #pragma unroll
    for (int k3=0; k3<3; k3++){
      int u = w + 8*k3;
      int fa = u>>3, ef = u&7;
      #pragma unroll
      for (int r=0;r<4;r++){
        int px = 16*fa + lg*4 + r;
        if (px >= 45) continue;
        int e = ef*16 + lr;
        int n = y*45 + px;
        size_t rb = (size_t)(n*2+b);
        int ch = h*128 + e;
        float v = acc[k3][r];
        if (ch < 512) v *= bf2f(Ug[rb*512 + ch]);
        OutL[rb*ldo + ch] = bf16_rne(v);
      }
    }
#undef S_LOAD
#undef S_WRITE
#undef V_LOAD
  }
}

extern "C" void kernel_launch(void* const* d_in, const int* in_sizes, int n_in,
                              void* d_out, int out_size, void* d_ws, size_t ws_size,
                              hipStream_t stream)
{
  const float* tgt    = (const float*)d_in[0];
  const float* id_emb = (const float*)d_in[1];
  const float* ln1_g  = (const float*)d_in[2];
  const float* ln1_b  = (const float*)d_in[3];
  const float* W_qv   = (const float*)d_in[4];
  const float* b_qv   = (const float*)d_in[5];
  const float* W_u    = (const float*)d_in[6];
  const float* b_u    = (const float*)d_in[7];
  const float* W_idv  = (const float*)d_in[8];
  const float* b_idv  = (const float*)d_in[9];
  const float* lt_Wo  = (const float*)d_in[10];
  const float* lt_bo  = (const float*)d_in[11];
  const float* Wrel   = (const float*)d_in[12];
  const float* brel   = (const float*)d_in[13];
  const float* st_Wo  = (const float*)d_in[14];
  const float* st_bo  = (const float*)d_in[15];
  const float* ln2_g  = (const float*)d_in[16];
  const float* ln2_b  = (const float*)d_in[17];
  const float* idln2_g= (const float*)d_in[18];
  const float* idln2_b= (const float*)d_in[19];
  const float* sa_Wqk = (const float*)d_in[20];
  const float* sa_bqk = (const float*)d_in[21];
  const float* sa_Wv  = (const float*)d_in[22];
  const float* sa_bv  = (const float*)d_in[23];
  const float* sa_Wu  = (const float*)d_in[24];
  const float* sa_bu  = (const float*)d_in[25];
  const float* sa_Wo  = (const float*)d_in[26];
  const float* sa_bo  = (const float*)d_in[27];
  float* out = (float*)d_out;
  float* ws  = (float*)d_ws;

  // ---- workspace carving (float units) ----
  float* newt  = ws;                                          // f32 4050x256
  float* tgtid = ws + 1036800;                                // f32 4050x256
  unsigned short* tgt_ln = (unsigned short*)(ws + 2073600);   // bf16 4050x256
  unsigned short* Qbuf   = (unsigned short*)(ws + 2592000);   // bf16 4050x256
  unsigned short* Vbuf   = (unsigned short*)(ws + 3110400);   // bf16 4050x1024
  unsigned short* Ubuf   = (unsigned short*)(ws + 5184000);   // bf16 4050x512
  unsigned short* Gbig   = (unsigned short*)(ws + 6220800);   // bf16 4050x2048
  unsigned short* Us2    = (unsigned short*)(ws + 10368000);  // bf16 4050x1024
  unsigned short* xbuf   = (unsigned short*)(ws + 12441600);  // bf16 4050x512
  unsigned*       Wpk    = (unsigned*)(ws + 13478400);        // 1,605,632 u32
  unsigned short* WrelBf = (unsigned short*)(ws + 15084032);  // 57,600 u16
  unsigned short* idBf   = (unsigned short*)(ws + 15112832);  // 1,036,800 u16

  const unsigned* Wcat1   = Wpk;             // [128][1280]
  const unsigned* Widv_pk = Wpk + 163840;    // [128][512]
  const unsigned* WcatT23 = Wpk + 229376;    // [1024][512]
  const unsigned* Wcat2   = Wpk + 753664;    // [256][2304]
  const unsigned* WsaWo   = Wpk + 1343488;   // [512][512]

  const int M = NBS;
  dim3 blk(256);
  int gx = (M+63)/64;   // 64

  // merged: weight/id convert (blocks 0..10546) + first LayerNorm (blocks 10547..14596)
  convert_ln_kernel<<<14597, blk, 0, stream>>>(W_qv, W_u, W_idv, lt_Wo, st_Wo,
      sa_Wqk, sa_Wv, sa_Wu, sa_Wo, Wrel, id_emb, (unsigned*)Wpk, WrelBf, idBf,
      tgt, ln1_g, ln1_b, tgt_ln);

  gemm_mfma_kernel<1><<<dim3(gx, 20), blk, 0, stream>>>(
      tgt_ln,256, Wcat1,1280, b_qv, b_u, nullptr, Qbuf, Vbuf, Ubuf, M, 256);
  gemm_mfma_kernel<0><<<dim3(gx, 8), blk, 0, stream>>>(
      idBf,256, Widv_pk,512, b_idv, nullptr, nullptr, Vbuf, nullptr, nullptr, M, 256);

  // fused flash#1 + local, roles interleaved in physical bid space
  attn_fused_kernel<<<dim3(1232), dim3(512), 0, stream>>>(
      Qbuf, Vbuf, Ubuf, Gbig, 512, 2048, WrelBf, brel, Gbig+1024);

  gemm_mfma_kernel<3><<<dim3(gx, 8), blk, 0, stream>>>(
      Gbig,2048, WcatT23,512, lt_bo, st_bo, nullptr, newt, tgtid, (void*)tgt, M, 2048);

  ln_dual_kernel<<<M, 256, 0, stream>>>(newt, tgtid, ln2_g, ln2_b, idln2_g, idln2_b, xbuf);

  gemm_mfma_kernel<2><<<dim3(gx, 36), blk, 0, stream>>>(
      xbuf,512, Wcat2,2304, sa_bqk, sa_bv, sa_bu, Qbuf, Vbuf, Us2, M, 512);

  // flash#2 only (512 blocks, identity map)
  attn_fused_kernel<<<dim3(512), dim3(512), 0, stream>>>(
      Qbuf, Vbuf, Us2, Gbig, 1024, 2048, WrelBf, brel, Gbig+1024);

  gemm_mfma_kernel<4><<<dim3(gx, 8), blk, 0, stream>>>(
      Gbig,2048, WsaWo,512, sa_bo, nullptr, nullptr, out, newt, tgtid, M, 1024);
}

// Round 26
// 258.150 us; speedup vs baseline: 1.0338x; 1.0207x over previous
//
#include <hip/hip_runtime.h>
#include <math.h>

#define NTOK 2025
#define NBS  4050   // NTOK * BS
#define BSZ  2

typedef __attribute__((ext_vector_type(8))) short bf16x8;
typedef __attribute__((ext_vector_type(4))) float f32x4;

__device__ __forceinline__ float silu_f(float v){ return v / (1.f + __expf(-v)); }

__device__ __forceinline__ unsigned short bf16_rne(float f){
  union { float f; unsigned u; } v; v.f = f;
  unsigned u = v.u;
  return (unsigned short)((u + 0x7FFFu + ((u >> 16) & 1u)) >> 16);
}
__device__ __forceinline__ float bf2f(unsigned short u){
  union { unsigned u; float f; } v; v.u = ((unsigned)u)<<16; return v.f;
}
__device__ __forceinline__ bf16x8 zero_bf8(){
  bf16x8 r;
  #pragma unroll
  for (int j=0;j<8;j++) r[j]=0;
  return r;
}
__device__ __forceinline__ float fexp2(float x){
  float r; asm("v_exp_f32 %0, %1" : "=v"(r) : "v"(x)); return r;
}
__device__ __forceinline__ unsigned cvt_pk_bf16(float lo, float hi){
  unsigned r; asm("v_cvt_pk_bf16_f32 %0, %1, %2" : "=v"(r) : "v"(lo), "v"(hi)); return r;
}

#define QSC 0.5050097642f      /* 32^(-1/4) * sqrt(log2 e): QK product carries log2e/sqrt(32) */
#define LOG2E 1.4426950408889634f

#define VPACK2(dst, stride, e0, aw, cw) \
  (dst)[(e0)*(stride)]     = ((aw) & 0xffffu) | ((cw) << 16); \
  (dst)[((e0)+1)*(stride)] = ((aw) >> 16)     | ((cw) & 0xffff0000u);

// ---------------- prologue convert + first LayerNorm (merged, independent work) ----------------
__global__ __launch_bounds__(256) void convert_ln_kernel(
    const float* __restrict__ Wqv, const float* __restrict__ Wu, const float* __restrict__ Widv,
    const float* __restrict__ ltWo, const float* __restrict__ stWo, const float* __restrict__ saWqk,
    const float* __restrict__ saWv, const float* __restrict__ saWu, const float* __restrict__ saWo,
    const float* __restrict__ Wrel, const float* __restrict__ idemb,
    unsigned* __restrict__ outPk, unsigned short* __restrict__ outWrel, unsigned short* __restrict__ outId,
    const float* __restrict__ lnin, const float* __restrict__ lng,
    const float* __restrict__ lnb, unsigned short* __restrict__ lnout)
{
  if (blockIdx.x < 10547){
    int idx = blockIdx.x*256 + threadIdx.x;
    if (idx < 1605632){
      float lo, hi;
      if (idx < 163840){
        int k2 = idx/1280, n = idx - k2*1280;
        const float* W; int ldw, nn;
        if (n < 768){ W=Wqv; ldw=768; nn=n; } else { W=Wu; ldw=512; nn=n-768; }
        lo = W[(size_t)(2*k2)*ldw + nn]; hi = W[(size_t)(2*k2+1)*ldw + nn];
      } else if (idx < 229376){
        int rel = idx-163840; int k2 = rel>>9, n = rel&511;
        lo = Widv[(size_t)(2*k2)*512 + n]; hi = Widv[(size_t)(2*k2+1)*512 + n];
      } else if (idx < 753664){
        int rel = idx-229376; int k2 = rel>>9, n = rel&511;
        int kk = 2*k2;
        if (kk < 1024){ lo = ltWo[(size_t)kk*512 + n]; hi = ltWo[(size_t)(kk+1)*512 + n]; }
        else          { lo = stWo[(size_t)(kk-1024)*512 + n]; hi = stWo[(size_t)(kk-1023)*512 + n]; }
      } else if (idx < 1343488){
        int rel = idx-753664; int k2 = rel/2304, n = rel - k2*2304;
        const float* W; int ldw, nn;
        if (n < 256){ W=saWqk; ldw=256; nn=n; }
        else if (n < 1280){ W=saWv; ldw=1024; nn=n-256; }
        else { W=saWu; ldw=1024; nn=n-1280; }
        lo = W[(size_t)(2*k2)*ldw + nn]; hi = W[(size_t)(2*k2+1)*ldw + nn];
      } else {
        int rel = idx-1343488; int k2 = rel>>9, n = rel&511;
        lo = saWo[(size_t)(2*k2)*512 + n]; hi = saWo[(size_t)(2*k2+1)*512 + n];
      }
      outPk[idx] = (unsigned)bf16_rne(lo) | ((unsigned)bf16_rne(hi)<<16);
    } else if (idx < 1663232){
      int r = idx - 1605632;
      outWrel[r] = bf16_rne(Wrel[r] * QSC);
    } else if (idx < 2700032){
      int r = idx - 1663232;
      outId[r] = bf16_rne(idemb[r]);
    }
  } else {
    int row = blockIdx.x - 10547;
    int t = threadIdx.x;
    float x = lnin[(size_t)row*256 + t];
    float s = x, s2 = x*x;
    #pragma unroll
    for (int o=32; o>0; o>>=1){ s += __shfl_xor(s,o); s2 += __shfl_xor(s2,o); }
    __shared__ float w1[4], w2[4];
    __shared__ float mean_s, rstd_s;
    int wid = t>>6, lane = t&63;
    if (lane==0){ w1[wid]=s; w2[wid]=s2; }
    __syncthreads();
    if (t==0){
      float S  = w1[0]+w1[1]+w1[2]+w1[3];
      float S2 = w2[0]+w2[1]+w2[2]+w2[3];
      float m = S*(1.f/256.f);
      float v = S2*(1.f/256.f) - m*m;
      mean_s = m; rstd_s = rsqrtf(v + 1e-5f);
    }
    __syncthreads();
    lnout[(size_t)row*256 + t] = bf16_rne((x-mean_s)*rstd_s*lng[t] + lnb[t]);
  }
}

// ---------------- dual LayerNorm ----------------
__global__ __launch_bounds__(256) void ln_dual_kernel(
    const float* __restrict__ newt, const float* __restrict__ tgtid,
    const float* __restrict__ g1, const float* __restrict__ b1,
    const float* __restrict__ g2, const float* __restrict__ b2,
    unsigned short* __restrict__ xbuf)
{
  int row = blockIdx.x;
  int t = threadIdx.x;
  float x1 = newt[(size_t)row*256 + t];
  float x2 = tgtid[(size_t)row*256 + t];
  float s1=x1, q1=x1*x1, s2v=x2, q2=x2*x2;
  #pragma unroll
  for (int o=32; o>0; o>>=1){
    s1 += __shfl_xor(s1,o); q1 += __shfl_xor(q1,o);
    s2v += __shfl_xor(s2v,o); q2 += __shfl_xor(q2,o);
  }
  __shared__ float w[4][4];
  __shared__ float st[4];
  int wid = t>>6, lane = t&63;
  if (lane==0){ w[wid][0]=s1; w[wid][1]=q1; w[wid][2]=s2v; w[wid][3]=q2; }
  __syncthreads();
  if (t==0){
    float S1=0,Q1=0,S2=0,Q2=0;
    #pragma unroll
    for (int i=0;i<4;i++){ S1+=w[i][0]; Q1+=w[i][1]; S2+=w[i][2]; Q2+=w[i][3]; }
    float m1=S1*(1.f/256.f), v1=Q1*(1.f/256.f)-m1*m1;
    float m2=S2*(1.f/256.f), v2=Q2*(1.f/256.f)-m2*m2;
    st[0]=m1; st[1]=rsqrtf(v1+1e-5f); st[2]=m2; st[3]=rsqrtf(v2+1e-5f);
  }
  __syncthreads();
  xbuf[(size_t)row*512 + t]       = bf16_rne((x1-st[0])*st[1]*g1[t] + b1[t]);
  xbuf[(size_t)row*512 + 256 + t] = bf16_rne((x2-st[2])*st[3]*g2[t] + b2[t]);
}

// ---------------- MFMA bf16 GEMM, BK=64, fused routing epilogues ----------------
template<int ROUTE>
__global__ __launch_bounds__(256) void gemm_mfma_kernel(
    const unsigned short* __restrict__ A, int lda,
    const unsigned* __restrict__ Bpk, int ldn,
    const float* __restrict__ bias0, const float* __restrict__ bias1, const float* __restrict__ bias2,
    void* __restrict__ P0, void* __restrict__ P1, void* __restrict__ P2,
    int M, int K)
{
  __shared__ __align__(16) unsigned short As[2*64*40];
  __shared__ __align__(16) unsigned Bst[2*64*20];
  const int t = threadIdx.x;
  const int w = t>>6, l = t&63, lr = l&15, lg = l>>4;
  const int m0 = blockIdx.x*64, n0 = blockIdx.y*64;

  const int ar = t>>2,  ak  = (t&3)<<3;
  const int bc = t&63,  bk4 = (t>>6)<<2;

  f32x4 acc[4];
  #pragma unroll
  for (int i=0;i<4;i++) acc[i]=(f32x4){0.f,0.f,0.f,0.f};

  bf16x8 aR0 = zero_bf8(), aR1 = zero_bf8();
  unsigned bR[8];
  {
    if (m0+ar < M){
      aR0 = *reinterpret_cast<const bf16x8*>(&A[(size_t)(m0+ar)*lda + ak]);
      aR1 = *reinterpret_cast<const bf16x8*>(&A[(size_t)(m0+ar)*lda + 32 + ak]);
    }
    #pragma unroll
    for (int j=0;j<4;j++){
      bR[j]   = Bpk[(size_t)(bk4+j)*ldn + n0 + bc];
      bR[4+j] = Bpk[(size_t)(16+bk4+j)*ldn + n0 + bc];
    }
  }

  const int NR = K>>6;
  for (int rr=0; rr<NR; rr++){
    __syncthreads();
    {
      *reinterpret_cast<bf16x8*>(&As[0*2560 + ar*40 + ak]) = aR0;
      *reinterpret_cast<bf16x8*>(&As[1*2560 + ar*40 + ak]) = aR1;
      *reinterpret_cast<uint4*>(&Bst[0*1280 + bc*20 + bk4]) = make_uint4(bR[0],bR[1],bR[2],bR[3]);
      *reinterpret_cast<uint4*>(&Bst[1*1280 + bc*20 + bk4]) = make_uint4(bR[4],bR[5],bR[6],bR[7]);
    }
    __syncthreads();
    if (rr+1 < NR){
      int k0 = (rr+1)<<6;
      if (m0+ar < M){
        aR0 = *reinterpret_cast<const bf16x8*>(&A[(size_t)(m0+ar)*lda + k0 + ak]);
        aR1 = *reinterpret_cast<const bf16x8*>(&A[(size_t)(m0+ar)*lda + k0 + 32 + ak]);
      }
      #pragma unroll
      for (int j=0;j<4;j++){
        bR[j]   = Bpk[(size_t)((k0>>1)+bk4+j)*ldn + n0 + bc];
        bR[4+j] = Bpk[(size_t)((k0>>1)+16+bk4+j)*ldn + n0 + bc];
      }
    }
    bf16x8 af0 = *reinterpret_cast<const bf16x8*>(&As[0*2560 + (w*16+lr)*40 + lg*8]);
    #pragma unroll
    for (int cf=0; cf<4; cf++){
      bf16x8 bf = *reinterpret_cast<const bf16x8*>(&Bst[0*1280 + (cf*16+lr)*20 + lg*4]);
      acc[cf] = __builtin_amdgcn_mfma_f32_16x16x32_bf16(af0, bf, acc[cf], 0,0,0);
    }
    bf16x8 af1 = *reinterpret_cast<const bf16x8*>(&As[1*2560 + (w*16+lr)*40 + lg*8]);
    #pragma unroll
    for (int cf=0; cf<4; cf++){
      bf16x8 bf = *reinterpret_cast<const bf16x8*>(&Bst[1*1280 + (cf*16+lr)*20 + lg*4]);
      acc[cf] = __builtin_amdgcn_mfma_f32_16x16x32_bf16(af1, bf, acc[cf], 0,0,0);
    }
  }

  #pragma unroll
  for (int cf=0; cf<4; cf++){
    int col = n0 + cf*16 + lr;
    float bb;
    if (ROUTE==2) bb = (col<256) ? bias0[col] : (col<1280 ? bias1[col-256] : bias2[col-1280]);
    if (ROUTE==3) bb = bias0[col] + bias1[col];
    if (ROUTE==4) bb = bias0[col];
    #pragma unroll
    for (int r=0;r<4;r++){
      int row = m0 + w*16 + lg*4 + r;
      if (row >= M) continue;
      float v = acc[cf][r] + bb;
      if (ROUTE==2){
        if (col < 256)       ((unsigned short*)P0)[(size_t)row*256 + col] = bf16_rne(v*QSC);
        else if (col < 1280) ((unsigned short*)P1)[(size_t)row*1024 + col-256] = bf16_rne(silu_f(v));
        else                 ((unsigned short*)P2)[(size_t)row*1024 + col-1280] = bf16_rne(silu_f(v));
      }
      if (ROUTE==3){
        if (col < 256) ((float*)P0)[(size_t)row*256 + col] = v + ((const float*)P2)[(size_t)row*256 + col];
        else           ((float*)P1)[(size_t)row*256 + col-256] = v;
      }
      if (ROUTE==4){
        if (col < 256) ((float*)P0)[(size_t)row*256 + col] = v + ((const float*)P1)[(size_t)row*256 + col];
        else           ((float*)P0)[(size_t)NBS*256 + (size_t)row*256 + col-256] = v + ((const float*)P2)[(size_t)row*256 + col-256];
      }
    }
  }
}

// ---------------- dual-route GEMM: route1 (QV/U projections) + route0 (idV projection), one dispatch ----------------
__global__ __launch_bounds__(256) void gemm_dual_kernel(
    const unsigned short* __restrict__ A1, const unsigned* __restrict__ B1,
    const unsigned short* __restrict__ A0, const unsigned* __restrict__ B0,
    const float* __restrict__ b_qv, const float* __restrict__ b_u, const float* __restrict__ b_idv,
    unsigned short* __restrict__ Qbuf, unsigned short* __restrict__ Vbuf, unsigned short* __restrict__ Ubuf,
    int M)
{
  __shared__ __align__(16) unsigned short As[2*64*40];
  __shared__ __align__(16) unsigned Bst[2*64*20];
  const int t = threadIdx.x;
  const int w = t>>6, l = t&63, lr = l&15, lg = l>>4;
  const int m0 = blockIdx.x*64;
  const int yb = blockIdx.y;
  const bool isR1 = (yb < 20);
  const unsigned short* A = isR1 ? A1 : A0;
  const unsigned* Bpk     = isR1 ? B1 : B0;
  const int ldn = isR1 ? 1280 : 512;
  const int n0  = isR1 ? yb*64 : (yb-20)*64;

  const int ar = t>>2,  ak  = (t&3)<<3;
  const int bc = t&63,  bk4 = (t>>6)<<2;

  f32x4 acc[4];
  #pragma unroll
  for (int i=0;i<4;i++) acc[i]=(f32x4){0.f,0.f,0.f,0.f};

  bf16x8 aR0 = zero_bf8(), aR1 = zero_bf8();
  unsigned bR[8];
  {
    if (m0+ar < M){
      aR0 = *reinterpret_cast<const bf16x8*>(&A[(size_t)(m0+ar)*256 + ak]);
      aR1 = *reinterpret_cast<const bf16x8*>(&A[(size_t)(m0+ar)*256 + 32 + ak]);
    }
    #pragma unroll
    for (int j=0;j<4;j++){
      bR[j]   = Bpk[(size_t)(bk4+j)*ldn + n0 + bc];
      bR[4+j] = Bpk[(size_t)(16+bk4+j)*ldn + n0 + bc];
    }
  }

  const int NR = 4;   // K = 256
  for (int rr=0; rr<NR; rr++){
    __syncthreads();
    {
      *reinterpret_cast<bf16x8*>(&As[0*2560 + ar*40 + ak]) = aR0;
      *reinterpret_cast<bf16x8*>(&As[1*2560 + ar*40 + ak]) = aR1;
      *reinterpret_cast<uint4*>(&Bst[0*1280 + bc*20 + bk4]) = make_uint4(bR[0],bR[1],bR[2],bR[3]);
      *reinterpret_cast<uint4*>(&Bst[1*1280 + bc*20 + bk4]) = make_uint4(bR[4],bR[5],bR[6],bR[7]);
    }
    __syncthreads();
    if (rr+1 < NR){
      int k0 = (rr+1)<<6;
      if (m0+ar < M){
        aR0 = *reinterpret_cast<const bf16x8*>(&A[(size_t)(m0+ar)*256 + k0 + ak]);
        aR1 = *reinterpret_cast<const bf16x8*>(&A[(size_t)(m0+ar)*256 + k0 + 32 + ak]);
      }
      #pragma unroll
      for (int j=0;j<4;j++){
        bR[j]   = Bpk[(size_t)((k0>>1)+bk4+j)*ldn + n0 + bc];
        bR[4+j] = Bpk[(size_t)((k0>>1)+16+bk4+j)*ldn + n0 + bc];
      }
    }
    bf16x8 af0 = *reinterpret_cast<const bf16x8*>(&As[0*2560 + (w*16+lr)*40 + lg*8]);
    #pragma unroll
    for (int cf=0; cf<4; cf++){
      bf16x8 bf = *reinterpret_cast<const bf16x8*>(&Bst[0*1280 + (cf*16+lr)*20 + lg*4]);
      acc[cf] = __builtin_amdgcn_mfma_f32_16x16x32_bf16(af0, bf, acc[cf], 0,0,0);
    }
    bf16x8 af1 = *reinterpret_cast<const bf16x8*>(&As[1*2560 + (w*16+lr)*40 + lg*8]);
    #pragma unroll
    for (int cf=0; cf<4; cf++){
      bf16x8 bf = *reinterpret_cast<const bf16x8*>(&Bst[1*1280 + (cf*16+lr)*20 + lg*4]);
      acc[cf] = __builtin_amdgcn_mfma_f32_16x16x32_bf16(af1, bf, acc[cf], 0,0,0);
    }
  }

  #pragma unroll
  for (int cf=0; cf<4; cf++){
    int col = n0 + cf*16 + lr;
    float bb = isR1 ? ((col<768) ? b_qv[col] : b_u[col-768]) : b_idv[col];
    #pragma unroll
    for (int r=0;r<4;r++){
      int row = m0 + w*16 + lg*4 + r;
      if (row >= M) continue;
      float v = acc[cf][r] + bb;
      if (isR1){
        if (col < 256)      Qbuf[(size_t)row*256 + col] = bf16_rne(v*QSC);
        else if (col < 768) Vbuf[(size_t)row*1024 + col-256] = bf16_rne(silu_f(v));
        else                Ubuf[(size_t)row*512 + col-768] = bf16_rne(silu_f(v));
      } else {
        Vbuf[(size_t)row*1024 + 512 + col] = bf16_rne(silu_f(v));
      }
    }
  }
}

// ---------------- fused attention: compact-LDS flash (3 blocks/CU) + local (8-wave)
// Round-20 flash path; lrun cross-lane reduction deferred out of the k-loop.
__global__ __launch_bounds__(512) void attn_fused_kernel(
    const unsigned short* __restrict__ Qp, const unsigned short* __restrict__ Vp,
    const unsigned short* __restrict__ Ug, unsigned short* __restrict__ OutF,
    int gateW, int ldo,
    const unsigned short* __restrict__ WrelBf, const float* __restrict__ brel_g,
    unsigned short* __restrict__ OutL)
{
  __shared__ __align__(16) unsigned char smem[53248];
  const int t = threadIdx.x;
  const f32x4 zero4 = (f32x4){0.f,0.f,0.f,0.f};
  const uint4 z4 = make_uint4(0,0,0,0);

  int fbid = 0, lbid = 0;
  bool isFlash;
  if (gridDim.x == 512){
    isFlash = true; fbid = blockIdx.x;
  } else {
    int bidx = blockIdx.x;
    if (bidx < 256){ isFlash = true;  fbid = bidx; }
    else if (bidx < 616){ isFlash = false; lbid = bidx - 256; }
    else if (bidx < 872){ isFlash = true;  fbid = bidx - 360; }
    else { isFlash = false; lbid = bidx - 512; }
  }

  if (isFlash){
    // ================= FLASH PATH =================
    unsigned short* Ks  = (unsigned short*)smem;           // 2*64*40 u16 = 10240B
    unsigned*       Vt2 = (unsigned*)(smem + 10240);       // 2*128*32 u32 = 32768B
    unsigned short* Pb  = (unsigned short*)(smem + 43008); // 8*16*40 u16 = 10240B

    const int w  = t >> 6;
    const int half = w >> 2;
    const int wl = w & 3;
    const int th = t & 255;
    const int l  = t & 63;
    const int lr = l & 15;
    const int lg = l >> 4;

    const int bid = fbid;
    const int xcd = bid & 7, rrr = bid >> 3;
    const int grp = (rrr >> 5)*8 + xcd;
    const int h = grp >> 1, b = grp & 1;
    const int r0 = (rrr & 31) * 64;

    unsigned short* KsH = &Ks[half*64*40];
    unsigned*       VtH = &Vt2[half*128*32];

    bf16x8 qf = zero_bf8();
    {
      int n = r0 + wl*16 + lr;
      if (n < NTOK) qf = *reinterpret_cast<const bf16x8*>(&Qp[(size_t)(n*2+b)*256 + h*32 + lg*8]);
    }

    f32x4 acc[8];
    #pragma unroll
    for (int i=0;i<8;i++) acc[i] = (f32x4){0.f,0.f,0.f,0.f};
    float lrun = 0.f;

    const int key = th & 63, kdh = th >> 6;
    const int kp  = th & 31, vdh = th >> 5;
    const int ktBase = half*16;

    bf16x8 kReg = zero_bf8();
    uint4 vA0=z4, vA1=z4, vC0=z4, vC1=z4;
    {
      int k0p = ktBase*64;
      int n = k0p + key;
      if (n < NTOK) kReg = *reinterpret_cast<const bf16x8*>(&Qp[(size_t)(n*2+b)*256 + h*32 + kdh*8]);
      int n0i = k0p + kp*2, n1i = n0i + 1;
      const uint4* v0 = reinterpret_cast<const uint4*>(Vp + (size_t)(n0i*2+b)*1024 + h*128 + vdh*16);
      const uint4* v1 = reinterpret_cast<const uint4*>(Vp + (size_t)(n1i*2+b)*1024 + h*128 + vdh*16);
      if (n0i < NTOK){ vA0 = v0[0]; vA1 = v0[1]; }
      if (n1i < NTOK){ vC0 = v1[0]; vC1 = v1[1]; }
    }

    for (int it=0; it<16; it++){
      const int k0 = (ktBase + it)*64;
      __syncthreads();

      *reinterpret_cast<bf16x8*>(&KsH[key*40 + kdh*8]) = kReg;
      { // V tile pack, stride-32 XOR swizzled: col' = kp ^ ((row&7)<<2)
        unsigned* Vb = VtH + (vdh*16)*32;
        #define VP2S(e0, aw, cw) \
          Vb[(e0)*32   + (kp ^ (((e0)&7)<<2))]       = ((aw)&0xffffu) | ((cw)<<16); \
          Vb[((e0)+1)*32 + (kp ^ ((((e0)+1)&7)<<2))] = ((aw)>>16)     | ((cw)&0xffff0000u);
        VP2S(0,  vA0.x, vC0.x)
        VP2S(2,  vA0.y, vC0.y)
        VP2S(4,  vA0.z, vC0.z)
        VP2S(6,  vA0.w, vC0.w)
        VP2S(8,  vA1.x, vC1.x)
        VP2S(10, vA1.y, vC1.y)
        VP2S(12, vA1.z, vC1.z)
        VP2S(14, vA1.w, vC1.w)
        #undef VP2S
      }
      __syncthreads();

      if (it+1 < 16){
        int k0n = k0 + 64;
        int n = k0n + key;
        kReg = zero_bf8();
        if (n < NTOK) kReg = *reinterpret_cast<const bf16x8*>(&Qp[(size_t)(n*2+b)*256 + h*32 + kdh*8]);
        int n0i = k0n + kp*2, n1i = n0i + 1;
        const uint4* v0 = reinterpret_cast<const uint4*>(Vp + (size_t)(n0i*2+b)*1024 + h*128 + vdh*16);
        const uint4* v1 = reinterpret_cast<const uint4*>(Vp + (size_t)(n1i*2+b)*1024 + h*128 + vdh*16);
        vA0=z4; vA1=z4; vC0=z4; vC1=z4;
        if (n0i < NTOK){ vA0 = v0[0]; vA1 = v0[1]; }
        if (n1i < NTOK){ vC0 = v1[0]; vC1 = v1[1]; }
      }

      // swapped QK^T: s[f][r] = S[q=lr][key=k0+16f+4lg+r]
      f32x4 s[4];
      #pragma unroll
      for (int f=0;f<4;f++){
        bf16x8 kb = *reinterpret_cast<const bf16x8*>(&KsH[(16*f + lr)*40 + lg*8]);
        s[f] = __builtin_amdgcn_mfma_f32_16x16x32_bf16(kb, qf, zero4, 0, 0, 0);
      }
      #pragma unroll
      for (int f=0;f<4;f++)
        #pragma unroll
        for (int r=0;r<4;r++)
          s[f][r] = fexp2(s[f][r]);
      if (k0 + 64 > NTOK){
        #pragma unroll
        for (int f=0;f<4;f++)
          #pragma unroll
          for (int r=0;r<4;r++)
            if (k0 + 16*f + 4*lg + r >= NTOK) s[f][r] = 0.f;
      }

      { // lane-local row sum (cross-lane reduce deferred to after the loop)
        float ps = 0.f;
        #pragma unroll
        for (int f=0;f<4;f++){
          ps += s[f][0]; ps += s[f][1]; ps += s[f][2]; ps += s[f][3];
        }
        lrun += ps;
      }

      unsigned short* pb = &Pb[w*16*40];
      // sub-phase A: keys 0..31 (f=0,1)
      #pragma unroll
      for (int f=0;f<2;f++){
        unsigned w0 = cvt_pk_bf16(s[f][0], s[f][1]);
        unsigned w1 = cvt_pk_bf16(s[f][2], s[f][3]);
        *reinterpret_cast<uint2*>(&pb[lr*40 + 16*f + 4*lg]) = make_uint2(w0, w1);
      }
      {
        bf16x8 pa0 = *reinterpret_cast<const bf16x8*>(&pb[lr*40 + lg*8]);
        #pragma unroll
        for (int c=0;c<8;c++){
          bf16x8 vb0 = *reinterpret_cast<const bf16x8*>(&VtH[(c*16+lr)*32 + ((lg*4) ^ ((lr&7)<<2))]);
          acc[c] = __builtin_amdgcn_mfma_f32_16x16x32_bf16(pa0, vb0, acc[c], 0, 0, 0);
        }
      }
      // sub-phase B: keys 32..63 (f=2,3) reuse strip
      #pragma unroll
      for (int f=2;f<4;f++){
        unsigned w0 = cvt_pk_bf16(s[f][0], s[f][1]);
        unsigned w1 = cvt_pk_bf16(s[f][2], s[f][3]);
        *reinterpret_cast<uint2*>(&pb[lr*40 + 16*(f-2) + 4*lg]) = make_uint2(w0, w1);
      }
      {
        bf16x8 pa1 = *reinterpret_cast<const bf16x8*>(&pb[lr*40 + lg*8]);
        #pragma unroll
        for (int c=0;c<8;c++){
          bf16x8 vb1 = *reinterpret_cast<const bf16x8*>(&VtH[(c*16+lr)*32 + ((16 + lg*4) ^ ((lr&7)<<2))]);
          acc[c] = __builtin_amdgcn_mfma_f32_16x16x32_bf16(pa1, vb1, acc[c], 0, 0, 0);
        }
      }
    }

    // deferred cross-lane reduction (sum of shuffles == shuffle of sums)
    lrun += __shfl_xor(lrun, 16);
    lrun += __shfl_xor(lrun, 32);

    // ---- combine halves: plain sums (swizzled exchange) ----
    __syncthreads();
    float* exA = (float*)Vt2;   // 256 slots x 32 f32, col ^ (slot&31)
    float* exM = (float*)Ks;    // 256 slots x 1 f32
    const int slot = wl*64 + l;
    if (half == 1){
      exM[slot] = lrun;
      #pragma unroll
      for (int c=0;c<8;c++)
        #pragma unroll
        for (int r=0;r<4;r++)
          exA[slot*32 + ((c*4+r) ^ (slot&31))] = acc[c][r];
    }
    __syncthreads();
    if (half == 1) return;

    lrun += exM[slot];
    #pragma unroll
    for (int c=0;c<8;c++)
      #pragma unroll
      for (int r=0;r<4;r++)
        acc[c][r] += exA[slot*32 + ((c*4+r) ^ (slot&31))];

    float linv[4];
    #pragma unroll
    for (int r=0;r<4;r++) linv[r] = 1.f / __shfl(lrun, lg*4 + r);

    #pragma unroll
    for (int r=0;r<4;r++){
      int n = r0 + wl*16 + lg*4 + r;
      if (n >= NTOK) continue;
      size_t rb = (size_t)(n*2+b);
      const unsigned short* ugr = Ug + rb*gateW;
      unsigned short* orow = OutF + rb*ldo + h*128;
      #pragma unroll
      for (int c=0;c<8;c++){
        int dv = c*16 + lr;
        int ch = h*128 + dv;
        float v = acc[c][r]*linv[r];
        if (ch < gateW) v *= bf2f(ugr[ch]);
        orow[dv] = bf16_rne(v);
      }
    }
    return;
  }

  // ================= LOCAL PATH (8 waves) =================
  {
    unsigned short* scb = (unsigned short*)smem;           // 45*226 u16 = 20340B
    float* ubuf = (float*)(smem + 20352);
    unsigned short* Qs = (unsigned short*)ubuf;            // [48*40]
    unsigned short* Wk = Qs + 48*40;
    unsigned short* Abuf = (unsigned short*)ubuf;          // phase C P~ [48][72 u16]
    unsigned*       Vt2L = (unsigned*)(ubuf + 1728);       // phase C V^ [128][36]

    const int w = t>>6, l = t&63;
    const int lr = l&15, lg = l>>4;

    const int xcd = lbid & 7, rrr = lbid >> 3;     // rrr in [0,90)
    const int grp = (rrr/45)*8 + xcd;
    const int h = grp >> 1, b = grp & 1;
    const int y = rrr % 45;

    const unsigned short NEGBF = bf16_rne(-1e9f);

    for (int i=t; i<45*226; i+=512) scb[i] = NEGBF;

    for (int idx=t; idx<192; idx+=512){
      int row = idx>>2, c = (idx&3)<<3;
      bf16x8 v = zero_bf8();
      if (row < 45) v = *reinterpret_cast<const bf16x8*>(&Qp[(size_t)((y*45+row)*2+b)*256 + h*32 + c]);
      *reinterpret_cast<bf16x8*>(&Qs[row*40 + c]) = v;
    }
    for (int idx=t; idx<960; idx+=512){
      int row = idx>>2, c = (idx&3)<<3;
      bf16x8 v = zero_bf8();
      if (row < 225) v = *reinterpret_cast<const bf16x8*>(&WrelBf[((size_t)h*225 + row)*32 + c]);
      *reinterpret_cast<bf16x8*>(&Wk[row*40 + c]) = v;
    }
    __syncthreads();

    bf16x8 sv[3];
#define S_LOAD(c0v, ncv) { \
    _Pragma("unroll") \
    for (int k=0;k<3;k++){ \
      int idx = t + k*512; \
      sv[k] = zero_bf8(); \
      if (idx < (ncv)*192){ \
        int d = idx/192, r192 = idx - d*192; \
        int row = r192>>2, c = (r192&3)<<3; \
        int yy = y + (c0v) + d - 7; \
        if (yy>=0 && yy<45 && row<45) \
          sv[k] = *reinterpret_cast<const bf16x8*>(&Qp[(size_t)((yy*45+row)*2+b)*256 + h*32 + c]); \
      } } }
#define S_WRITE(c0v, ncv) { \
    _Pragma("unroll") \
    for (int k=0;k<3;k++){ \
      int idx = t + k*512; \
      if (idx < (ncv)*192){ \
        int d = idx/192, r192 = idx - d*192; \
        int row = r192>>2, c = (r192&3)<<3; \
        int yy = y + (c0v) + d - 7; \
        if (yy>=0 && yy<45) \
          *reinterpret_cast<bf16x8*>(&Wk[d*1920 + row*40 + c]) = sv[k]; \
      } } }

    S_LOAD(0, 6)

    // ---- R pass (8 waves) ----
    for (int fo=w; fo<15; fo+=8){
      bf16x8 wb = *reinterpret_cast<const bf16x8*>(&Wk[(16*fo+lr)*40 + lg*8]);
      int o = 16*fo + lr;
      int dyo = o/15, dxo = o - dyo*15;
      int yyo = y + dyo - 7;
      bool ovalid = (o < 225) && (yyo >= 0) && (yyo < 45);
      float bb = ovalid ? brel_g[h*225+o]*LOG2E : 0.f;
      #pragma unroll
      for (int fa=0; fa<3; fa++){
        bf16x8 qa = *reinterpret_cast<const bf16x8*>(&Qs[(16*fa+lr)*40 + lg*8]);
        f32x4 rr = __builtin_amdgcn_mfma_f32_16x16x32_bf16(qa, wb, zero4, 0, 0, 0);
        if (ovalid){
          #pragma unroll
          for (int r=0;r<4;r++){
            int px = 16*fa + lg*4 + r;
            int xx = px + dxo - 7;
            if (px < 45 && xx >= 0 && xx < 45)
              scb[px*226 + o] = bf16_rne(rr[r] + bb);
          }
        }
      }
    }

    // ---- S pass: 3 chunks (8 waves) ----
    for (int ci=0; ci<3; ci++){
      int c0 = ci*6;
      int nc = (ci<2) ? 6 : 3;
      __syncthreads();
      S_WRITE(c0, nc)
      __syncthreads();
      if (ci==0) S_LOAD(6, 6)
      if (ci==1) S_LOAD(12, 3)
      for (int u=w; u<nc*7; u+=8){
        int d = u/7, pi = u - d*7;
        int dy = c0 + d, yy = y + dy - 7;
        if (yy < 0 || yy >= 45) continue;
        int fa = (0x2110210u >> (4*pi)) & 7;
        int fb = (0x1201210u >> (4*pi)) & 7;
        bf16x8 qa = *reinterpret_cast<const bf16x8*>(&Qs[(16*fa+lr)*40 + lg*8]);
        bf16x8 kb = *reinterpret_cast<const bf16x8*>(&Wk[d*1920 + (16*fb+lr)*40 + lg*8]);
        f32x4 s = __builtin_amdgcn_mfma_f32_16x16x32_bf16(qa, kb, zero4, 0, 0, 0);
        int xx = 16*fb + lr;
        #pragma unroll
        for (int r=0;r<4;r++){
          int px = 16*fa + lg*4 + r;
          int dx = xx - px + 7;
          if (px < 45 && xx < 45 && dx >= 0 && dx < 15){
            int o = dy*15+dx;
            scb[px*226 + o] = bf16_rne(bf2f(scb[px*226 + o]) + s[r]);
          }
        }
      }
    }
    __syncthreads();

    // ---- static softmax (scores carry log2e -> native exp2) ----
    {
      int grp2 = t>>5, lane = t&31;
      for (int px = grp2; px < 45; px += 16){
        float sum = 0.f;
        for (int o=lane; o<225; o+=32){
          float p = fexp2(bf2f(scb[px*226 + o]));
          scb[px*226 + o] = bf16_rne(p);
          sum += p;
        }
        #pragma unroll
        for (int off=16; off>0; off>>=1) sum += __shfl_xor(sum, off);
        float inv = 1.f/sum;
        for (int o=lane; o<225; o+=32)
          scb[px*226 + o] = bf16_rne(bf2f(scb[px*226 + o]) * inv);
      }
    }

    // ---- phase C: per-dy MFMA aggregation (8 waves, 3 accs each) ----
    f32x4 acc[3];
    #pragma unroll
    for (int i=0;i<3;i++) acc[i]=(f32x4){0.f,0.f,0.f,0.f};

    const int dyLo = (y < 7) ? (7-y) : 0;
    const int dyHi = (y > 37) ? (51-y) : 14;
    const int kp = t&31, vg = (t>>5)&7, vs = t>>8;
    const int rb0 = vg*16 + vs*8;
    uint4 vA0=z4, vC0=z4;

#define V_LOAD(dyv) { \
      int yy = y + (dyv) - 7; \
      int xx0 = kp*2 - 7, xx1 = xx0 + 1; \
      const uint4* v0p = reinterpret_cast<const uint4*>(Vp + ((size_t)((yy*45+xx0)*2+b))*1024 + h*128 + rb0); \
      const uint4* v1p = reinterpret_cast<const uint4*>(Vp + ((size_t)((yy*45+xx1)*2+b))*1024 + h*128 + rb0); \
      vA0=z4; vC0=z4; \
      if (xx0 >= 0 && xx0 < 45) vA0 = v0p[0]; \
      if (xx1 >= 0 && xx1 < 45) vC0 = v1p[0]; }

    V_LOAD(dyLo)

    for (int dy=dyLo; dy<=dyHi; dy++){
      __syncthreads();

      { // build P~
        unsigned* A32 = (unsigned*)Abuf;
        for (int i=t; i<48*32; i+=512){
          int px = i>>5, wd = i&31;
          int kk0 = wd*2, kk1 = kk0+1;
          unsigned p0 = 0, p1 = 0;
          if (px < 45){
            int dx0 = kk0 - px, dx1 = kk1 - px;
            if (dx0 >= 0 && dx0 < 15 && kk0 >= 7 && kk0 < 52) p0 = scb[px*226 + dy*15+dx0];
            if (dx1 >= 0 && dx1 < 15 && kk1 >= 7 && kk1 < 52) p1 = scb[px*226 + dy*15+dx1];
          }
          A32[px*36 + wd] = p0 | (p1<<16);
        }
      }
      { // stage V^ (8 rows per thread)
        unsigned* dst = &Vt2L[rb0*36 + kp];
        VPACK2(dst, 36, 0, vA0.x, vC0.x)
        VPACK2(dst, 36, 2, vA0.y, vC0.y)
        VPACK2(dst, 36, 4, vA0.z, vC0.z)
        VPACK2(dst, 36, 6, vA0.w, vC0.w)
      }
      __syncthreads();

      if (dy < dyHi) V_LOAD(dy+1)

      #pragma unroll
      for (int k3=0; k3<3; k3++){
        int u = w + 8*k3;
        int fa = u>>3, ef = u&7;
        bf16x8 a0 = *reinterpret_cast<const bf16x8*>(&Abuf[(16*fa+lr)*72 + 0*32 + lg*8]);
        bf16x8 b0 = *reinterpret_cast<const bf16x8*>(&Vt2L[(ef*16+lr)*36 + 0*16 + lg*4]);
        acc[k3] = __builtin_amdgcn_mfma_f32_16x16x32_bf16(a0, b0, acc[k3], 0,0,0);
        bf16x8 a1 = *reinterpret_cast<const bf16x8*>(&Abuf[(16*fa+lr)*72 + 1*32 + lg*8]);
        bf16x8 b1 = *reinterpret_cast<const bf16x8*>(&Vt2L[(ef*16+lr)*36 + 1*16 + lg*4]);
        acc[k3] = __builtin_amdgcn_mfma_f32_16x16x32_bf16(a1, b1, acc[k3], 0,0,0);
      }
    }

    // ---- epilogue ----
    #pragma unroll
    for (int k3=0; k3<3; k3++){
      int u = w + 8*k3;
      int fa = u>>3, ef = u&7;
      #pragma unroll
      for (int r=0;r<4;r++){
        int px = 16*fa + lg*4 + r;
        if (px >= 45) continue;
        int e = ef*16 + lr;
        int n = y*45 + px;
        size_t rb = (size_t)(n*2+b);
        int ch = h*128 + e;
        float v = acc[k3][r];
        if (ch < 512) v *= bf2f(Ug[rb*512 + ch]);
        OutL[rb*ldo + ch] = bf16_rne(v);
      }
    }
#undef S_LOAD
#undef S_WRITE
#undef V_LOAD
  }
}

extern "C" void kernel_launch(void* const* d_in, const int* in_sizes, int n_in,
                              void* d_out, int out_size, void* d_ws, size_t ws_size,
                              hipStream_t stream)
{
  const float* tgt    = (const float*)d_in[0];
  const float* id_emb = (const float*)d_in[1];
  const float* ln1_g  = (const float*)d_in[2];
  const float* ln1_b  = (const float*)d_in[3];
  const float* W_qv   = (const float*)d_in[4];
  const float* b_qv   = (const float*)d_in[5];
  const float* W_u    = (const float*)d_in[6];
  const float* b_u    = (const float*)d_in[7];
  const float* W_idv  = (const float*)d_in[8];
  const float* b_idv  = (const float*)d_in[9];
  const float* lt_Wo  = (const float*)d_in[10];
  const float* lt_bo  = (const float*)d_in[11];
  const float* Wrel   = (const float*)d_in[12];
  const float* brel   = (const float*)d_in[13];
  const float* st_Wo  = (const float*)d_in[14];
  const float* st_bo  = (const float*)d_in[15];
  const float* ln2_g  = (const float*)d_in[16];
  const float* ln2_b  = (const float*)d_in[17];
  const float* idln2_g= (const float*)d_in[18];
  const float* idln2_b= (const float*)d_in[19];
  const float* sa_Wqk = (const float*)d_in[20];
  const float* sa_bqk = (const float*)d_in[21];
  const float* sa_Wv  = (const float*)d_in[22];
  const float* sa_bv  = (const float*)d_in[23];
  const float* sa_Wu  = (const float*)d_in[24];
  const float* sa_bu  = (const float*)d_in[25];
  const float* sa_Wo  = (const float*)d_in[26];
  const float* sa_bo  = (const float*)d_in[27];
  float* out = (float*)d_out;
  float* ws  = (float*)d_ws;

  // ---- workspace carving (float units) ----
  float* newt  = ws;                                          // f32 4050x256
  float* tgtid = ws + 1036800;                                // f32 4050x256
  unsigned short* tgt_ln = (unsigned short*)(ws + 2073600);   // bf16 4050x256
  unsigned short* Qbuf   = (unsigned short*)(ws + 2592000);   // bf16 4050x256
  unsigned short* Vbuf   = (unsigned short*)(ws + 3110400);   // bf16 4050x1024
  unsigned short* Ubuf   = (unsigned short*)(ws + 5184000);   // bf16 4050x512
  unsigned short* Gbig   = (unsigned short*)(ws + 6220800);   // bf16 4050x2048
  unsigned short* Us2    = (unsigned short*)(ws + 10368000);  // bf16 4050x1024
  unsigned short* xbuf   = (unsigned short*)(ws + 12441600);  // bf16 4050x512
  unsigned*       Wpk    = (unsigned*)(ws + 13478400);        // 1,605,632 u32
  unsigned short* WrelBf = (unsigned short*)(ws + 15084032);  // 57,600 u16
  unsigned short* idBf   = (unsigned short*)(ws + 15112832);  // 1,036,800 u16

  const unsigned* Wcat1   = Wpk;             // [128][1280]
  const unsigned* Widv_pk = Wpk + 163840;    // [128][512]
  const unsigned* WcatT23 = Wpk + 229376;    // [1024][512]
  const unsigned* Wcat2   = Wpk + 753664;    // [256][2304]
  const unsigned* WsaWo   = Wpk + 1343488;   // [512][512]

  const int M = NBS;
  dim3 blk(256);
  int gx = (M+63)/64;   // 64

  // merged: weight/id convert (blocks 0..10546) + first LayerNorm (blocks 10547..14596)
  convert_ln_kernel<<<14597, blk, 0, stream>>>(W_qv, W_u, W_idv, lt_Wo, st_Wo,
      sa_Wqk, sa_Wv, sa_Wu, sa_Wo, Wrel, id_emb, (unsigned*)Wpk, WrelBf, idBf,
      tgt, ln1_g, ln1_b, tgt_ln);

  // merged: route1 (QV/U projections, y 0..19) + route0 (idV projection, y 20..27)
  gemm_dual_kernel<<<dim3(gx, 28), blk, 0, stream>>>(
      tgt_ln, Wcat1, idBf, Widv_pk, b_qv, b_u, b_idv, Qbuf, Vbuf, Ubuf, M);

  // fused flash#1 + local, roles interleaved in physical bid space
  attn_fused_kernel<<<dim3(1232), dim3(512), 0, stream>>>(
      Qbuf, Vbuf, Ubuf, Gbig, 512, 2048, WrelBf, brel, Gbig+1024);

  gemm_mfma_kernel<3><<<dim3(gx, 8), blk, 0, stream>>>(
      Gbig,2048, WcatT23,512, lt_bo, st_bo, nullptr, newt, tgtid, (void*)tgt, M, 2048);

  ln_dual_kernel<<<M, 256, 0, stream>>>(newt, tgtid, ln2_g, ln2_b, idln2_g, idln2_b, xbuf);

  gemm_mfma_kernel<2><<<dim3(gx, 36), blk, 0, stream>>>(
      xbuf,512, Wcat2,2304, sa_bqk, sa_bv, sa_bu, Qbuf, Vbuf, Us2, M, 512);

  // flash#2 only (512 blocks, identity map)
  attn_fused_kernel<<<dim3(512), dim3(512), 0, stream>>>(
      Qbuf, Vbuf, Us2, Gbig, 1024, 2048, WrelBf, brel, Gbig+1024);

  gemm_mfma_kernel<4><<<dim3(gx, 8), blk, 0, stream>>>(
      Gbig,2048, WsaWo,512, sa_bo, nullptr, nullptr, out, newt, tgtid, M, 1024);
}